// Round 3
// baseline (512.250 us; speedup 1.0000x reference)
//
#include <hip/hip_runtime.h>

// Problem constants (fixed by setup_inputs): N=2048, D=512, H=8, dh=64, max_iter=5.
// Identity: exp(s/t + log(kern*yw+eps)) = exp(s/(8t)) * (kern*yw+eps).
// R3 architecture: E is NEVER materialized (all E-touching kernels were pinned
// at ~1.6-1.9 TB/s regardless of layout; recompute via MFMA is ~8x cheaper).
//  - ms_zS: per iteration, one fused sweep computes z[h][n] = sum_m E*g and
//    S[h][n][3] = sum_m E*g*x_m (single pass: S accumulated before invz known;
//    xyz_new = (1/8) sum_h invz*S).  q-frags persistent, scores via MFMA,
//    exp+g+mask+accumulate in registers, 16-lane xor-reduce, partial slices.
//  - ms_fin: tiny reduce of 16 slices -> invz, xyz_dst (and invzb on last).
//  - g_kern: materialize g (mask folded in) once, 8 MB, for av.
//  - av_mfma: recomputes its E-tiles in-block (wave-private As/gs, no barriers).
//  - scores_rows and the 64 MB Ebf buffer are deleted.

typedef __attribute__((ext_vector_type(8))) short bf16x8;
typedef __attribute__((ext_vector_type(4))) float f32x4;

__device__ __forceinline__ unsigned short f2bf(float f) {
    unsigned int u = __float_as_uint(f);
    u += 0x7fff + ((u >> 16) & 1);   // RNE (inputs finite)
    return (unsigned short)(u >> 16);
}
__device__ __forceinline__ float bf2f(unsigned short u) {
    return __uint_as_float((unsigned int)u << 16);
}

union EU { bf16x8 v; unsigned short u[8]; };

// ---------------------------------------------------------------------------
// Convert strf + Wq/Wk/Wv/Wo fp32->bf16 (sW = [4][262144]) and dmask->byte.
// 8 elems/thread; grid 3072x256 exact.
// ---------------------------------------------------------------------------
__global__ __launch_bounds__(256)
void conv_all(const float* __restrict__ strf,
              const float* __restrict__ Wq, const float* __restrict__ Wk,
              const float* __restrict__ Wv, const float* __restrict__ Wo,
              const int* __restrict__ dmask,
              unsigned short* __restrict__ sA, unsigned short* __restrict__ sW,
              unsigned char* __restrict__ mby)
{
    const long base = (long)(blockIdx.x * 256 + threadIdx.x) * 8;
    if (base >= 2097152) {
        const long rel = base - 2097152;
        int4 a = *reinterpret_cast<const int4*>(dmask + rel);
        int4 b = *reinterpret_cast<const int4*>(dmask + rel + 4);
        unsigned long long p = 0;
        p |= (a.x > 0) ? 0x01ULL : 0;  p |= (a.y > 0) ? 0x0100ULL : 0;
        p |= (a.z > 0) ? 0x010000ULL : 0;  p |= (a.w > 0) ? 0x01000000ULL : 0;
        p |= (b.x > 0) ? 0x0100000000ULL : 0;  p |= (b.y > 0) ? 0x010000000000ULL : 0;
        p |= (b.z > 0) ? 0x01000000000000ULL : 0;  p |= (b.w > 0) ? 0x0100000000000000ULL : 0;
        *reinterpret_cast<unsigned long long*>(mby + rel) = p;
        return;
    }
    const float* src;
    unsigned short* dst;
    if (base < 1048576) {
        src = strf + base; dst = sA + base;
    } else {
        const long rel = base - 1048576;
        const int seg = (int)(rel >> 18);
        const long off = rel & 262143;
        const float* Ws[4] = {Wq, Wk, Wv, Wo};
        src = Ws[seg] + off;
        dst = sW + (long)seg * 262144 + off;
    }
    float4 a = *reinterpret_cast<const float4*>(src);
    float4 b = *reinterpret_cast<const float4*>(src + 4);
    EU o;
    o.u[0] = f2bf(a.x); o.u[1] = f2bf(a.y); o.u[2] = f2bf(a.z); o.u[3] = f2bf(a.w);
    o.u[4] = f2bf(b.x); o.u[5] = f2bf(b.y); o.u[6] = f2bf(b.z); o.u[7] = f2bf(b.w);
    *reinterpret_cast<bf16x8*>(dst) = o.v;
}

// ---------------------------------------------------------------------------
// q/k/v projection via bf16 MFMA. grid (32 n-tiles, 8 d-tiles, 3).
// z=0 -> qh, z=1 -> kh, z=2 -> vT (transposed direct store).
// ---------------------------------------------------------------------------
__global__ __launch_bounds__(256)
void qkv_mfma(const unsigned short* __restrict__ sA,
              const unsigned short* __restrict__ sW,
              const float* __restrict__ bq, const float* __restrict__ bk,
              const float* __restrict__ bv,
              unsigned short* __restrict__ qh, unsigned short* __restrict__ kh,
              unsigned short* __restrict__ vT)
{
    const int z  = blockIdx.z;
    const int bx = blockIdx.x;
    const int by = blockIdx.y;
    const int tid = threadIdx.x;
    const int wv = tid >> 6;
    const int lane = tid & 63;
    const int row  = lane & 15;
    const int koct = (lane >> 4) * 8;
    const int n0 = bx * 64;

    const unsigned short* Ap = sA + (long)(n0 + wv * 16 + row) * 512;
    const unsigned short* Bp = sW + (long)z * 262144 + (long)(by * 64 + row) * 512;

    f32x4 acc[4] = {};
#pragma unroll
    for (int k0 = 0; k0 < 512; k0 += 32) {
        bf16x8 a = *reinterpret_cast<const bf16x8*>(Ap + k0 + koct);
#pragma unroll
        for (int t = 0; t < 4; t++) {
            bf16x8 b = *reinterpret_cast<const bf16x8*>(Bp + (long)(t * 16) * 512 + k0 + koct);
            acc[t] = __builtin_amdgcn_mfma_f32_16x16x32_bf16(a, b, acc[t], 0, 0, 0);
        }
    }

    if (z == 2) {
        const int rbase = n0 + wv * 16 + (lane >> 4) * 4;
#pragma unroll
        for (int t = 0; t < 4; t++) {
            const int d = by * 64 + t * 16 + (lane & 15);
            const float bb = bv[d];
            ushort4 o;
            o.x = f2bf(acc[t][0] + bb); o.y = f2bf(acc[t][1] + bb);
            o.z = f2bf(acc[t][2] + bb); o.w = f2bf(acc[t][3] + bb);
            *reinterpret_cast<ushort4*>(vT + (long)d * 2048 + rbase) = o;
        }
        return;
    }

    __shared__ float ls[64][68];
    const int lrb = wv * 16 + (lane >> 4) * 4;
    const int lcb = lane & 15;
#pragma unroll
    for (int t = 0; t < 4; t++)
#pragma unroll
        for (int r = 0; r < 4; r++)
            ls[lrb + r][t * 16 + lcb] = acc[t][r];
    __syncthreads();

    const float* bias = (z == 0) ? bq : bk;
    unsigned short* dst = (z == 0) ? qh : kh;
    const int r2 = tid >> 2;
    const int c2 = (tid & 3) * 16;
    float sv[16];
#pragma unroll
    for (int j = 0; j < 4; j++) {
        float4 s = *reinterpret_cast<const float4*>(&ls[r2][c2 + j * 4]);
        float4 bb = *reinterpret_cast<const float4*>(bias + by * 64 + c2 + j * 4);
        sv[j*4+0] = s.x + bb.x; sv[j*4+1] = s.y + bb.y;
        sv[j*4+2] = s.z + bb.z; sv[j*4+3] = s.w + bb.w;
    }
    EU o0, o1;
#pragma unroll
    for (int j = 0; j < 8; j++) { o0.u[j] = f2bf(sv[j]); o1.u[j] = f2bf(sv[8 + j]); }
    unsigned short* dp = dst + (long)(n0 + r2) * 512 + by * 64 + c2;
    *reinterpret_cast<bf16x8*>(dp)     = o0.v;
    *reinterpret_cast<bf16x8*>(dp + 8) = o1.v;
}

// ---------------------------------------------------------------------------
// ms_zS: one fused mean-shift sweep.  grid (128 row-tiles, 4 m-splits),
// block 256 = 4 waves; wave owns a 128-m chunk of rows n0..n0+15.
// Per (hh-pass of 4 heads): q-frags persistent; per 16-m tile: scores via
// 2 MFMA per head, e = exp(score*scale), g (masked) computed once per tile,
// accumulate z += e*g and S += e*g*x_m in registers.  16-lane xor-reduce,
// partial slice (z,Sx,Sy,Sz) written as float4 per (n,h).
// E never touches memory.
// ---------------------------------------------------------------------------
__global__ __launch_bounds__(256)
void ms_zS(const unsigned short* __restrict__ qh,
           const unsigned short* __restrict__ kh,
           const unsigned char* __restrict__ mby,
           const float* __restrict__ xyz_src,
           const float* __restrict__ y_hat,
           const float* __restrict__ tptr,
           const float* __restrict__ bwp,
           float* __restrict__ Pzs)              // [16][2048][8] float4
{
    const int n0 = blockIdx.x * 16;
    const int mc = blockIdx.y * 512;
    const int tid = threadIdx.x;
    const int lane = tid & 63;
    const int wv = tid >> 6;
    const int q = lane >> 4;
    const int mcol = lane & 15;
    const int arow = lane & 15;
    const int koct = q * 8;

    __shared__ float sxn[16], syn[16], szn[16], ssn[16];
    __shared__ float smx[512], smy[512], smz[512], ssq[512], syh[512];

    if (tid < 16) {
        const float x = xyz_src[(n0 + tid) * 3 + 0];
        const float y = xyz_src[(n0 + tid) * 3 + 1];
        const float z = xyz_src[(n0 + tid) * 3 + 2];
        sxn[tid] = x; syn[tid] = y; szn[tid] = z; ssn[tid] = x*x + y*y + z*z;
    }
#pragma unroll
    for (int k = 0; k < 2; k++) {
        const int ml = tid * 2 + k;
        const int mg = mc + ml;
        const float x = xyz_src[mg * 3 + 0];
        const float y = xyz_src[mg * 3 + 1];
        const float z = xyz_src[mg * 3 + 2];
        smx[ml] = x; smy[ml] = y; smz[ml] = z;
        ssq[ml] = x*x + y*y + z*z;
        syh[ml] = y_hat[mg];
    }
    __syncthreads();

    const float scale = 1.0f / (8.0f * tptr[0]);
    const float bw = bwp[0];
    const float c2k = 1.0f / (2.0f * bw * bw);

    float xn[4], yn[4], zn[4], sq4[4];
#pragma unroll
    for (int r = 0; r < 4; r++) {
        xn[r] = sxn[q * 4 + r]; yn[r] = syn[q * 4 + r];
        zn[r] = szn[q * 4 + r]; sq4[r] = ssn[q * 4 + r];
    }

    const int mwave = mc + wv * 128;
    const int slice = blockIdx.y * 4 + wv;

#pragma unroll
    for (int hh = 0; hh < 8; hh += 4) {
        bf16x8 aq0[4], aq1[4];
#pragma unroll
        for (int h4 = 0; h4 < 4; h4++) {
            const unsigned short* Ap = qh + (long)(n0 + arow) * 512 + (hh + h4) * 64;
            aq0[h4] = *reinterpret_cast<const bf16x8*>(Ap + koct);
            aq1[h4] = *reinterpret_cast<const bf16x8*>(Ap + 32 + koct);
        }
        float zc[4][4] = {};
        float Sx[4][4] = {}, Sy[4][4] = {}, Sz[4][4] = {};

#pragma unroll
        for (int mt = 0; mt < 8; mt++) {
            const int ml = wv * 128 + mt * 16 + mcol;
            const float xm = smx[ml], ym = smy[ml], zm = smz[ml];
            const float sm = ssq[ml], yhm = syh[ml];
            // masked g per output row (h-independent)
            float gm[4];
#pragma unroll
            for (int r = 0; r < 4; r++) {
                const float d2 = sq4[r] + sm
                               - 2.0f * (xn[r]*xm + yn[r]*ym + zn[r]*zm);
                const float gv = __expf(-d2 * c2k) * yhm + 1e-9f;
                const unsigned char mk =
                    mby[(long)(n0 + q * 4 + r) * 2048 + mc + wv * 128 + mt * 16 + mcol];
                gm[r] = mk ? gv : 0.0f;
            }
#pragma unroll
            for (int h4 = 0; h4 < 4; h4++) {
                const unsigned short* Bk =
                    kh + (long)(mwave + mt * 16 + arow) * 512 + (hh + h4) * 64;
                bf16x8 b0 = *reinterpret_cast<const bf16x8*>(Bk + koct);
                bf16x8 b1 = *reinterpret_cast<const bf16x8*>(Bk + 32 + koct);
                f32x4 c = {};
                c = __builtin_amdgcn_mfma_f32_16x16x32_bf16(aq0[h4], b0, c, 0, 0, 0);
                c = __builtin_amdgcn_mfma_f32_16x16x32_bf16(aq1[h4], b1, c, 0, 0, 0);
#pragma unroll
                for (int r = 0; r < 4; r++) {
                    const float t = __expf(c[r] * scale) * gm[r];
                    zc[h4][r] += t;
                    Sx[h4][r] = fmaf(t, xm, Sx[h4][r]);
                    Sy[h4][r] = fmaf(t, ym, Sy[h4][r]);
                    Sz[h4][r] = fmaf(t, zm, Sz[h4][r]);
                }
            }
        }

        // reduce over the 16 m-columns (lanes sharing lane>>4)
#pragma unroll
        for (int d = 1; d < 16; d <<= 1) {
#pragma unroll
            for (int h4 = 0; h4 < 4; h4++)
#pragma unroll
                for (int r = 0; r < 4; r++) {
                    zc[h4][r] += __shfl_xor(zc[h4][r], d, 64);
                    Sx[h4][r] += __shfl_xor(Sx[h4][r], d, 64);
                    Sy[h4][r] += __shfl_xor(Sy[h4][r], d, 64);
                    Sz[h4][r] += __shfl_xor(Sz[h4][r], d, 64);
                }
        }
        if (mcol == 0) {
#pragma unroll
            for (int h4 = 0; h4 < 4; h4++)
#pragma unroll
                for (int r = 0; r < 4; r++) {
                    float4 o = make_float4(zc[h4][r], Sx[h4][r], Sy[h4][r], Sz[h4][r]);
                    *reinterpret_cast<float4*>(
                        Pzs + (((long)slice * 2048 + n0 + q * 4 + r) * 8 + hh + h4) * 4) = o;
                }
        }
    }
}

// ---------------------------------------------------------------------------
// ms_fin: reduce 16 partial slices -> z, S; invz = 1/z;
// xyz_dst[n] = (1/8) sum_h invz*S.  grid 64x256, thread = (n,h).
// ---------------------------------------------------------------------------
__global__ __launch_bounds__(256)
void ms_fin(const float* __restrict__ Pzs,
            float* __restrict__ xyz_dst,
            float* __restrict__ invzb,
            int wlast)
{
    const int gid = blockIdx.x * 256 + threadIdx.x;   // 0..16383
    const int n = gid >> 3;
    const int h = gid & 7;
    const float4* P4 = reinterpret_cast<const float4*>(Pzs);
    float z = 0.f, sx = 0.f, sy = 0.f, sz = 0.f;
#pragma unroll
    for (int s = 0; s < 16; s++) {
        float4 p = P4[((long)s * 2048 + n) * 8 + h];
        z += p.x; sx += p.y; sy += p.z; sz += p.w;
    }
    const float iz = 1.0f / z;
    if (wlast) invzb[h * 2048 + n] = iz;
    float cx = iz * sx, cy = iz * sy, cz = iz * sz;
#pragma unroll
    for (int d = 1; d < 8; d <<= 1) {
        cx += __shfl_xor(cx, d, 64);
        cy += __shfl_xor(cy, d, 64);
        cz += __shfl_xor(cz, d, 64);
    }
    if (h == 0) {
        xyz_dst[n * 3 + 0] = cx * 0.125f;
        xyz_dst[n * 3 + 1] = cy * 0.125f;
        xyz_dst[n * 3 + 2] = cz * 0.125f;
    }
}

// ---------------------------------------------------------------------------
// g_kern: gbf[n][m] = mask ? bf16(exp(-d2*c2k)*yh[m] + 1e-9) : 0, from the
// last iteration's input xyz.  grid (4 m-chunks, 256 row-tiles of 8).
// ---------------------------------------------------------------------------
__global__ __launch_bounds__(256)
void g_kern(const float* __restrict__ xyz4,
            const float* __restrict__ y_hat,
            const unsigned char* __restrict__ mby,
            const float* __restrict__ bwp,
            unsigned short* __restrict__ gbf)
{
    const int mc = blockIdx.x * 512;
    const int n0 = blockIdx.y * 8;
    const int tid = threadIdx.x;

    __shared__ float sxn[8], syn[8], szn[8], ssn[8];
    if (tid < 8) {
        const float x = xyz4[(n0 + tid) * 3 + 0];
        const float y = xyz4[(n0 + tid) * 3 + 1];
        const float z = xyz4[(n0 + tid) * 3 + 2];
        sxn[tid] = x; syn[tid] = y; szn[tid] = z; ssn[tid] = x*x + y*y + z*z;
    }
    __syncthreads();

    const float bw = bwp[0];
    const float c2k = 1.0f / (2.0f * bw * bw);
    const int m0 = mc + tid * 2;

    const float x0 = xyz4[m0 * 3 + 0], y0 = xyz4[m0 * 3 + 1], z0 = xyz4[m0 * 3 + 2];
    const float x1 = xyz4[m0 * 3 + 3], y1 = xyz4[m0 * 3 + 4], z1 = xyz4[m0 * 3 + 5];
    const float s0 = x0*x0 + y0*y0 + z0*z0;
    const float s1 = x1*x1 + y1*y1 + z1*z1;
    const float yh0 = y_hat[m0], yh1 = y_hat[m0 + 1];

#pragma unroll
    for (int r = 0; r < 8; r++) {
        const float xr = sxn[r], yr = syn[r], zr = szn[r], sr = ssn[r];
        const float d20 = sr + s0 - 2.0f * (xr*x0 + yr*y0 + zr*z0);
        const float d21 = sr + s1 - 2.0f * (xr*x1 + yr*y1 + zr*z1);
        const float g0 = __expf(-d20 * c2k) * yh0 + 1e-9f;
        const float g1 = __expf(-d21 * c2k) * yh1 + 1e-9f;
        const unsigned short mk2 = *reinterpret_cast<const unsigned short*>(
            mby + (long)(n0 + r) * 2048 + m0);
        ushort2 o;
        o.x = (mk2 & 0xff) ? f2bf(g0) : (unsigned short)0;
        o.y = (mk2 >> 8)   ? f2bf(g1) : (unsigned short)0;
        *reinterpret_cast<ushort2*>(gbf + (long)(n0 + r) * 2048 + m0) = o;
    }
}

// ---------------------------------------------------------------------------
// av_mfma: x_partial = (E ⊙ g) @ v, E recomputed in-block via MFMA.
// grid (32 n-tiles, 4 m-splits, 8 heads).  Everything wave-private:
// wave wv owns rows n0+wv*16..+15 of As/gs -> NO barriers in the kt loop.
// Per kt (128 m): stage g rows via global_load_lds, scores via 16 MFMA,
// exp*g -> As (bf16), then 16 MFMA against vT.  fp32 partial planes.
// ---------------------------------------------------------------------------
__global__ __launch_bounds__(256)
void av_mfma(const unsigned short* __restrict__ qh,
             const unsigned short* __restrict__ kh,
             const unsigned short* __restrict__ gbf,  // [2048][2048] (masked)
             const unsigned short* __restrict__ vT,   // [512][2048]
             const float* __restrict__ tptr,
             float* __restrict__ P)                   // [4][2048][512]
{
    const int h  = blockIdx.z;
    const int s  = blockIdx.y;
    const int bx = blockIdx.x;
    const int tid = threadIdx.x;
    const int wv = tid >> 6;
    const int lane = tid & 63;
    const int n0 = bx * 64;
    const int kc = s * 512;
    const int q = lane >> 4;
    const int mcol = lane & 15;
    const int arow = lane & 15;
    const int koct = q * 8;

    __shared__ unsigned short As[64][132];
    __shared__ unsigned short gs[64][128];

    const float scale = 1.0f / (8.0f * tptr[0]);

    const unsigned short* Ap = qh + (long)(n0 + wv * 16 + arow) * 512 + h * 64;
    const bf16x8 aq0 = *reinterpret_cast<const bf16x8*>(Ap + koct);
    const bf16x8 aq1 = *reinterpret_cast<const bf16x8*>(Ap + 32 + koct);

    f32x4 acc[4] = {};
    for (int kt = 0; kt < 4; kt++) {
        const int kb = kc + kt * 128;

        // stage this wave's 16 g-rows (4 KB) -> gs[wv*16..+15][0..127]
#pragma unroll
        for (int i = 0; i < 4; i++) {
            __builtin_amdgcn_global_load_lds(
                (const __attribute__((address_space(1))) unsigned int*)(
                    gbf + (long)(n0 + wv * 16 + i * 4 + (lane >> 4)) * 2048
                        + kb + (lane & 15) * 8),
                (__attribute__((address_space(3))) unsigned int*)&gs[wv * 16 + i * 4][0],
                16, 0, 0);
        }

        // scores for this wave's 16 rows x 128 m
        f32x4 c[8];
#pragma unroll
        for (int mt = 0; mt < 8; mt++) {
            const unsigned short* Bk =
                kh + (long)(kb + mt * 16 + arow) * 512 + h * 64;
            bf16x8 b0 = *reinterpret_cast<const bf16x8*>(Bk + koct);
            bf16x8 b1 = *reinterpret_cast<const bf16x8*>(Bk + 32 + koct);
            f32x4 cc = {};
            cc = __builtin_amdgcn_mfma_f32_16x16x32_bf16(aq0, b0, cc, 0, 0, 0);
            cc = __builtin_amdgcn_mfma_f32_16x16x32_bf16(aq1, b1, cc, 0, 0, 0);
            c[mt] = cc;
        }

        asm volatile("s_waitcnt vmcnt(0)" ::: "memory");  // gs DMA done (wave-private)

#pragma unroll
        for (int mt = 0; mt < 8; mt++)
#pragma unroll
            for (int r = 0; r < 4; r++) {
                const float e = __expf(c[mt][r] * scale);
                const unsigned short gv = gs[wv * 16 + q * 4 + r][mt * 16 + mcol];
                As[wv * 16 + q * 4 + r][mt * 16 + mcol] = f2bf(e * bf2f(gv));
            }

        // As rows are wave-private; compiler orders ds_write->ds_read.
#pragma unroll
        for (int k2 = 0; k2 < 128; k2 += 32) {
            bf16x8 a = *reinterpret_cast<const bf16x8*>(&As[wv * 16 + arow][k2 + koct]);
#pragma unroll
            for (int t = 0; t < 4; t++) {
                bf16x8 b = *reinterpret_cast<const bf16x8*>(
                    vT + ((long)h * 64 + t * 16 + arow) * 2048 + kb + k2 + koct);
                acc[t] = __builtin_amdgcn_mfma_f32_16x16x32_bf16(a, b, acc[t], 0, 0, 0);
            }
        }
    }

    float* Pp = P + (long)s * 1048576;
    const int rbase = n0 + wv * 16 + q * 4;
#pragma unroll
    for (int t = 0; t < 4; t++)
#pragma unroll
        for (int r = 0; r < 4; r++)
            Pp[(long)(rbase + r) * 512 + h * 64 + t * 16 + mcol] = acc[t][r];
}

// ---------------------------------------------------------------------------
// xc[n][d] bf16 = invz_h[n] * sum of 4 fp32 partials. 8 elems/thread.
// ---------------------------------------------------------------------------
__global__ __launch_bounds__(256)
void av_red(const float* __restrict__ P, const float* __restrict__ invzb,
            unsigned short* __restrict__ xc)
{
    const long idx = (long)(blockIdx.x * 256 + threadIdx.x) * 8;
    const int n = (int)(idx >> 9);
    const int d0 = (int)(idx & 511);
    const float iz = invzb[(d0 >> 6) * 2048 + n];
    float s[8] = {};
#pragma unroll
    for (int p = 0; p < 4; p++) {
        const float* pp = P + (long)p * 1048576 + idx;
        float4 a = *reinterpret_cast<const float4*>(pp);
        float4 b = *reinterpret_cast<const float4*>(pp + 4);
        s[0] += a.x; s[1] += a.y; s[2] += a.z; s[3] += a.w;
        s[4] += b.x; s[5] += b.y; s[6] += b.z; s[7] += b.w;
    }
    EU o;
#pragma unroll
    for (int j = 0; j < 8; j++) o.u[j] = f2bf(s[j] * iz);
    *reinterpret_cast<bf16x8*>(xc + idx) = o.v;
}

// ---------------------------------------------------------------------------
// out = xc @ Wo.T + bo via bf16 MFMA, fp32 out. grid (32 n-tiles, 8 d-tiles).
// ---------------------------------------------------------------------------
__global__ __launch_bounds__(256)
void out_mfma(const unsigned short* __restrict__ xc,
              const unsigned short* __restrict__ sW,   // seg 3 = Wo
              const float* __restrict__ bo,
              float* __restrict__ out)
{
    const int bx = blockIdx.x;
    const int by = blockIdx.y;
    const int wv = threadIdx.x >> 6;
    const int lane = threadIdx.x & 63;
    const int row  = lane & 15;
    const int koct = (lane >> 4) * 8;
    const int n0 = bx * 64;

    const unsigned short* Ap = xc + (long)(n0 + wv * 16 + row) * 512;
    const unsigned short* Bp = sW + 3L * 262144 + (long)(by * 64 + row) * 512;

    f32x4 acc[4] = {};
#pragma unroll
    for (int k0 = 0; k0 < 512; k0 += 32) {
        bf16x8 a = *reinterpret_cast<const bf16x8*>(Ap + k0 + koct);
#pragma unroll
        for (int t = 0; t < 4; t++) {
            bf16x8 b = *reinterpret_cast<const bf16x8*>(Bp + (long)(t * 16) * 512 + k0 + koct);
            acc[t] = __builtin_amdgcn_mfma_f32_16x16x32_bf16(a, b, acc[t], 0, 0, 0);
        }
    }

    const int rbase = n0 + wv * 16 + (lane >> 4) * 4;
    const int dcol = lane & 15;
#pragma unroll
    for (int t = 0; t < 4; t++) {
        const int col = by * 64 + t * 16 + dcol;
        const float bb = bo[col];
#pragma unroll
        for (int r = 0; r < 4; r++)
            out[(long)(rbase + r) * 512 + col] = acc[t][r] + bb;
    }
}

// ---------------------------------------------------------------------------
extern "C" void kernel_launch(void* const* d_in, const int* in_sizes, int n_in,
                              void* d_out, int out_size, void* d_ws, size_t ws_size,
                              hipStream_t stream)
{
    (void)in_sizes; (void)n_in; (void)out_size; (void)ws_size;

    const float* xyz   = (const float*)d_in[0];
    const float* strf  = (const float*)d_in[1];
    // d_in[2] esm_feat: dead code (DCE'd in reference)
    const float* yhat  = (const float*)d_in[3];
    const int*   dmask = (const int*)d_in[4];
    const float* tptr  = (const float*)d_in[5];
    const float* bwptr = (const float*)d_in[6];
    // d_in[7] max_iter = 5 (fixed)
    const float* Wq = (const float*)d_in[8];
    const float* bq = (const float*)d_in[9];
    const float* Wk = (const float*)d_in[10];
    const float* bk = (const float*)d_in[11];
    const float* Wv = (const float*)d_in[12];
    const float* bv = (const float*)d_in[13];
    const float* Wo = (const float*)d_in[14];
    const float* bo = (const float*)d_in[15];
    float* outp = (float*)d_out;

    char* wsb = (char*)d_ws;
    float* Ppart         = (float*)(wsb);                        // [4][2048][512] f32, 16 MB
    unsigned short* xc   = (unsigned short*)(wsb + (16L << 20)); // 2 MB
    unsigned short* sA   = (unsigned short*)(wsb + (18L << 20)); // 2 MB
    unsigned short* sW   = (unsigned short*)(wsb + (20L << 20)); // [4][262144] bf16, 2 MB
    unsigned short* qh   = (unsigned short*)(wsb + (22L << 20)); // 2 MB
    unsigned short* kh   = (unsigned short*)(wsb + (24L << 20)); // 2 MB
    unsigned short* vT   = (unsigned short*)(wsb + (26L << 20)); // 2 MB
    float* xyzA          = (float*)(wsb + (28L << 20));
    float* xyzB          = xyzA + 8192;
    unsigned char* mby   = (unsigned char*)(wsb + (30L << 20));  // 4 MB
    float* Pzs           = (float*)(wsb + (34L << 20));          // [16][2048][8][4] f32, 4 MB
    unsigned short* gbf  = (unsigned short*)(wsb + (40L << 20)); // [2048][2048] bf16, 8 MB
    float* invzb         = (float*)(wsb + (50L << 20));          // [8][2048] f32, 64 KB

    dim3 blk(256, 1, 1);

    // bf16 conversions (incl. Wo) + byte mask + q/k/v MFMA projections
    conv_all<<<dim3(3072), blk, 0, stream>>>(strf, Wq, Wk, Wv, Wo, dmask, sA, sW, mby);
    qkv_mfma<<<dim3(32, 8, 3), blk, 0, stream>>>(sA, sW, bq, bk, bv, qh, kh, vT);

    // 5 mean-shift iterations: fused z/S sweep (E recomputed) + tiny finish
    const float* src = xyz;
    float* dsts[5] = {xyzA, xyzB, xyzA, xyzB, outp};
    for (int it = 0; it < 5; it++) {
        ms_zS<<<dim3(128, 4), blk, 0, stream>>>(qh, kh, mby, src, yhat, tptr, bwptr, Pzs);
        ms_fin<<<dim3(64), blk, 0, stream>>>(Pzs, dsts[it], invzb, it == 4 ? 1 : 0);
        src = dsts[it];
    }

    // g (masked) from the LAST iteration's input xyz (= xyzB), then
    // x = (E ⊙ g) @ v with E recomputed in-block, reduce*invz, out-proj
    g_kern<<<dim3(4, 256), blk, 0, stream>>>(xyzB, yhat, mby, bwptr, gbf);
    av_mfma<<<dim3(32, 4, 8), blk, 0, stream>>>(qh, kh, gbf, vT, tptr, Ppart);
    av_red<<<dim3(512), blk, 0, stream>>>(Ppart, invzb, xc);
    out_mfma<<<dim3(32, 8), blk, 0, stream>>>(xc, sW, bo, outp + 6144);
}

// Round 4
// 428.871 us; speedup vs baseline: 1.1944x; 1.1944x over previous
//
#include <hip/hip_runtime.h>

// Problem constants (fixed by setup_inputs): N=2048, D=512, H=8, dh=64, max_iter=5.
// Identity: exp(s/t + log(kern*yw+eps)) = exp(s/(8t)) * (kern*yw+eps).
// R4 architecture: E never materialized. Mean-shift iteration uses a
// SWAPPED-operand score MFMA (A=K rows m, B=Q rows n) so each lane holds
// 4 consecutive m for one n -> exp+g+mask+accumulate are register-resident
// per-lane VALU (no LDS, no transpose). g/x_m/mask precomputed once per
// block into ~48 regs, reused across all 8 heads. m-reduce = 2 shfl_xor.
// R3's proven av path (g_kern + in-block E-recompute av_mfma) kept verbatim.

typedef __attribute__((ext_vector_type(8))) short bf16x8;
typedef __attribute__((ext_vector_type(4))) float f32x4;

__device__ __forceinline__ unsigned short f2bf(float f) {
    unsigned int u = __float_as_uint(f);
    u += 0x7fff + ((u >> 16) & 1);   // RNE (inputs finite)
    return (unsigned short)(u >> 16);
}
__device__ __forceinline__ float bf2f(unsigned short u) {
    return __uint_as_float((unsigned int)u << 16);
}

union EU { bf16x8 v; unsigned short u[8]; };

// ---------------------------------------------------------------------------
// Convert strf + Wq/Wk/Wv/Wo fp32->bf16 (sW = [4][262144]) and dmask->byte.
// 8 elems/thread; grid 3072x256 exact.
// ---------------------------------------------------------------------------
__global__ __launch_bounds__(256)
void conv_all(const float* __restrict__ strf,
              const float* __restrict__ Wq, const float* __restrict__ Wk,
              const float* __restrict__ Wv, const float* __restrict__ Wo,
              const int* __restrict__ dmask,
              unsigned short* __restrict__ sA, unsigned short* __restrict__ sW,
              unsigned char* __restrict__ mby)
{
    const long base = (long)(blockIdx.x * 256 + threadIdx.x) * 8;
    if (base >= 2097152) {
        const long rel = base - 2097152;
        int4 a = *reinterpret_cast<const int4*>(dmask + rel);
        int4 b = *reinterpret_cast<const int4*>(dmask + rel + 4);
        unsigned long long p = 0;
        p |= (a.x > 0) ? 0x01ULL : 0;  p |= (a.y > 0) ? 0x0100ULL : 0;
        p |= (a.z > 0) ? 0x010000ULL : 0;  p |= (a.w > 0) ? 0x01000000ULL : 0;
        p |= (b.x > 0) ? 0x0100000000ULL : 0;  p |= (b.y > 0) ? 0x010000000000ULL : 0;
        p |= (b.z > 0) ? 0x01000000000000ULL : 0;  p |= (b.w > 0) ? 0x0100000000000000ULL : 0;
        *reinterpret_cast<unsigned long long*>(mby + rel) = p;
        return;
    }
    const float* src;
    unsigned short* dst;
    if (base < 1048576) {
        src = strf + base; dst = sA + base;
    } else {
        const long rel = base - 1048576;
        const int seg = (int)(rel >> 18);
        const long off = rel & 262143;
        const float* Ws[4] = {Wq, Wk, Wv, Wo};
        src = Ws[seg] + off;
        dst = sW + (long)seg * 262144 + off;
    }
    float4 a = *reinterpret_cast<const float4*>(src);
    float4 b = *reinterpret_cast<const float4*>(src + 4);
    EU o;
    o.u[0] = f2bf(a.x); o.u[1] = f2bf(a.y); o.u[2] = f2bf(a.z); o.u[3] = f2bf(a.w);
    o.u[4] = f2bf(b.x); o.u[5] = f2bf(b.y); o.u[6] = f2bf(b.z); o.u[7] = f2bf(b.w);
    *reinterpret_cast<bf16x8*>(dst) = o.v;
}

// ---------------------------------------------------------------------------
// q/k/v projection via bf16 MFMA. grid (32 n-tiles, 8 d-tiles, 3).
// z=0 -> qh, z=1 -> kh, z=2 -> vT (transposed direct store).
// ---------------------------------------------------------------------------
__global__ __launch_bounds__(256)
void qkv_mfma(const unsigned short* __restrict__ sA,
              const unsigned short* __restrict__ sW,
              const float* __restrict__ bq, const float* __restrict__ bk,
              const float* __restrict__ bv,
              unsigned short* __restrict__ qh, unsigned short* __restrict__ kh,
              unsigned short* __restrict__ vT)
{
    const int z  = blockIdx.z;
    const int bx = blockIdx.x;
    const int by = blockIdx.y;
    const int tid = threadIdx.x;
    const int wv = tid >> 6;
    const int lane = tid & 63;
    const int row  = lane & 15;
    const int koct = (lane >> 4) * 8;
    const int n0 = bx * 64;

    const unsigned short* Ap = sA + (long)(n0 + wv * 16 + row) * 512;
    const unsigned short* Bp = sW + (long)z * 262144 + (long)(by * 64 + row) * 512;

    f32x4 acc[4] = {};
#pragma unroll
    for (int k0 = 0; k0 < 512; k0 += 32) {
        bf16x8 a = *reinterpret_cast<const bf16x8*>(Ap + k0 + koct);
#pragma unroll
        for (int t = 0; t < 4; t++) {
            bf16x8 b = *reinterpret_cast<const bf16x8*>(Bp + (long)(t * 16) * 512 + k0 + koct);
            acc[t] = __builtin_amdgcn_mfma_f32_16x16x32_bf16(a, b, acc[t], 0, 0, 0);
        }
    }

    if (z == 2) {
        const int rbase = n0 + wv * 16 + (lane >> 4) * 4;
#pragma unroll
        for (int t = 0; t < 4; t++) {
            const int d = by * 64 + t * 16 + (lane & 15);
            const float bb = bv[d];
            ushort4 o;
            o.x = f2bf(acc[t][0] + bb); o.y = f2bf(acc[t][1] + bb);
            o.z = f2bf(acc[t][2] + bb); o.w = f2bf(acc[t][3] + bb);
            *reinterpret_cast<ushort4*>(vT + (long)d * 2048 + rbase) = o;
        }
        return;
    }

    __shared__ float ls[64][68];
    const int lrb = wv * 16 + (lane >> 4) * 4;
    const int lcb = lane & 15;
#pragma unroll
    for (int t = 0; t < 4; t++)
#pragma unroll
        for (int r = 0; r < 4; r++)
            ls[lrb + r][t * 16 + lcb] = acc[t][r];
    __syncthreads();

    const float* bias = (z == 0) ? bq : bk;
    unsigned short* dst = (z == 0) ? qh : kh;
    const int r2 = tid >> 2;
    const int c2 = (tid & 3) * 16;
    float sv[16];
#pragma unroll
    for (int j = 0; j < 4; j++) {
        float4 s = *reinterpret_cast<const float4*>(&ls[r2][c2 + j * 4]);
        float4 bb = *reinterpret_cast<const float4*>(bias + by * 64 + c2 + j * 4);
        sv[j*4+0] = s.x + bb.x; sv[j*4+1] = s.y + bb.y;
        sv[j*4+2] = s.z + bb.z; sv[j*4+3] = s.w + bb.w;
    }
    EU o0, o1;
#pragma unroll
    for (int j = 0; j < 8; j++) { o0.u[j] = f2bf(sv[j]); o1.u[j] = f2bf(sv[8 + j]); }
    unsigned short* dp = dst + (long)(n0 + r2) * 512 + by * 64 + c2;
    *reinterpret_cast<bf16x8*>(dp)     = o0.v;
    *reinterpret_cast<bf16x8*>(dp + 8) = o1.v;
}

// ---------------------------------------------------------------------------
// ms_swp: one mean-shift sweep, register-resident.
// grid (64 n-tiles[32], 16 m-splits[128]); block 256 = 4 waves, wave owns
// m-chunk of 32 (2 tiles of 16).  Swapped score MFMA: A = kh rows m,
// B = qh rows n -> lane output: n = n0+ns*16+(lane&15), m = mw+t*16+grp*4+r
// (consecutive r).  g (mask+yh folded), x_m precomputed once per block into
// registers (float4 loads, 16-way broadcast).  Per h: 8 MFMA + per-lane
// exp/accumulate + 2 shfl_xor reduce + float4 slice store.  No LDS.
// ---------------------------------------------------------------------------
__global__ __launch_bounds__(256)
void ms_swp(const unsigned short* __restrict__ qh,
            const unsigned short* __restrict__ kh,
            const unsigned char* __restrict__ mby,
            const float* __restrict__ xyz_src,
            const float* __restrict__ y_hat,
            const float* __restrict__ tptr,
            const float* __restrict__ bwp,
            float* __restrict__ Pzs)            // [64][8][2048] float4, 16 MB
{
    const int n0 = blockIdx.x * 32;
    const int mb = blockIdx.y * 128;
    const int tid = threadIdx.x;
    const int wv = tid >> 6;
    const int lane = tid & 63;
    const int mw = mb + wv * 32;
    const int fr = lane & 15;
    const int grp = lane >> 4;
    const int koct = grp * 8;
    const int slice = blockIdx.y * 4 + wv;

    const float scale = 1.0f / (8.0f * tptr[0]);
    const float bw = bwp[0];
    const float c2k = 1.0f / (2.0f * bw * bw);

    // n-side scalars for the two n-subtiles
    float xn[2], yn[2], zn[2], sqn[2];
#pragma unroll
    for (int ns = 0; ns < 2; ns++) {
        const int n = n0 + ns * 16 + fr;
        const float x = xyz_src[n * 3 + 0];
        const float y = xyz_src[n * 3 + 1];
        const float z = xyz_src[n * 3 + 2];
        xn[ns] = x; yn[ns] = y; zn[ns] = z; sqn[ns] = x*x + y*y + z*z;
    }

    // m-side: 8 consecutive-ish m per lane: m = mw + t*16 + grp*4 + r
    float xm[8], ym[8], zm[8], gm[2][8];
#pragma unroll
    for (int t = 0; t < 2; t++) {
        const int m0 = mw + t * 16 + grp * 4;
        const float4 p0 = *reinterpret_cast<const float4*>(xyz_src + m0 * 3);
        const float4 p1 = *reinterpret_cast<const float4*>(xyz_src + m0 * 3 + 4);
        const float4 p2 = *reinterpret_cast<const float4*>(xyz_src + m0 * 3 + 8);
        xm[t*4+0]=p0.x; ym[t*4+0]=p0.y; zm[t*4+0]=p0.z;
        xm[t*4+1]=p0.w; ym[t*4+1]=p1.x; zm[t*4+1]=p1.y;
        xm[t*4+2]=p1.z; ym[t*4+2]=p1.w; zm[t*4+2]=p2.x;
        xm[t*4+3]=p2.y; ym[t*4+3]=p2.z; zm[t*4+3]=p2.w;
        const float4 yh4 = *reinterpret_cast<const float4*>(y_hat + m0);
        const float yhv[4] = {yh4.x, yh4.y, yh4.z, yh4.w};
        unsigned int mk[2];
        mk[0] = *reinterpret_cast<const unsigned int*>(mby + (long)(n0 + fr) * 2048 + m0);
        mk[1] = *reinterpret_cast<const unsigned int*>(mby + (long)(n0 + 16 + fr) * 2048 + m0);
#pragma unroll
        for (int r = 0; r < 4; r++) {
            const int e = t * 4 + r;
            const float sm = xm[e]*xm[e] + ym[e]*ym[e] + zm[e]*zm[e];
#pragma unroll
            for (int ns = 0; ns < 2; ns++) {
                const float d2 = sqn[ns] + sm
                               - 2.0f*(xn[ns]*xm[e] + yn[ns]*ym[e] + zn[ns]*zm[e]);
                const float gv = __expf(-d2 * c2k) * yhv[r] + 1e-9f;
                gm[ns][e] = ((mk[ns] >> (8*r)) & 0xff) ? gv : 0.0f;
            }
        }
    }

#pragma unroll 2
    for (int h = 0; h < 8; h++) {
        bf16x8 b0[2], b1[2];
#pragma unroll
        for (int ns = 0; ns < 2; ns++) {
            const unsigned short* Bp = qh + (long)(n0 + ns*16 + fr) * 512 + h * 64;
            b0[ns] = *reinterpret_cast<const bf16x8*>(Bp + koct);
            b1[ns] = *reinterpret_cast<const bf16x8*>(Bp + 32 + koct);
        }
        f32x4 c[2][2];
#pragma unroll
        for (int t = 0; t < 2; t++) {
            const unsigned short* Ap = kh + (long)(mw + t*16 + fr) * 512 + h * 64;
            bf16x8 a0 = *reinterpret_cast<const bf16x8*>(Ap + koct);
            bf16x8 a1 = *reinterpret_cast<const bf16x8*>(Ap + 32 + koct);
#pragma unroll
            for (int ns = 0; ns < 2; ns++) {
                f32x4 cc = {};
                cc = __builtin_amdgcn_mfma_f32_16x16x32_bf16(a0, b0[ns], cc, 0, 0, 0);
                cc = __builtin_amdgcn_mfma_f32_16x16x32_bf16(a1, b1[ns], cc, 0, 0, 0);
                c[t][ns] = cc;
            }
        }

        float z2[2] = {0.f, 0.f}, Sx2[2] = {0.f, 0.f};
        float Sy2[2] = {0.f, 0.f}, Sz2[2] = {0.f, 0.f};
#pragma unroll
        for (int t = 0; t < 2; t++)
#pragma unroll
        for (int ns = 0; ns < 2; ns++)
#pragma unroll
        for (int r = 0; r < 4; r++) {
            const int e = t * 4 + r;
            const float tt = __expf(c[t][ns][r] * scale) * gm[ns][e];
            z2[ns] += tt;
            Sx2[ns] = fmaf(tt, xm[e], Sx2[ns]);
            Sy2[ns] = fmaf(tt, ym[e], Sy2[ns]);
            Sz2[ns] = fmaf(tt, zm[e], Sz2[ns]);
        }
        // reduce over the 4 lane-groups (same fr = same n)
#pragma unroll
        for (int ns = 0; ns < 2; ns++) {
            z2[ns]  += __shfl_xor(z2[ns], 16, 64);
            z2[ns]  += __shfl_xor(z2[ns], 32, 64);
            Sx2[ns] += __shfl_xor(Sx2[ns], 16, 64);
            Sx2[ns] += __shfl_xor(Sx2[ns], 32, 64);
            Sy2[ns] += __shfl_xor(Sy2[ns], 16, 64);
            Sy2[ns] += __shfl_xor(Sy2[ns], 32, 64);
            Sz2[ns] += __shfl_xor(Sz2[ns], 16, 64);
            Sz2[ns] += __shfl_xor(Sz2[ns], 32, 64);
        }
        if (lane < 16) {
#pragma unroll
            for (int ns = 0; ns < 2; ns++) {
                float4 o = make_float4(z2[ns], Sx2[ns], Sy2[ns], Sz2[ns]);
                *reinterpret_cast<float4*>(
                    Pzs + (((long)slice * 8 + h) * 2048 + n0 + ns*16 + fr) * 4) = o;
            }
        }
    }
}

// ---------------------------------------------------------------------------
// ms_fin: reduce 64 slices -> invz, xyz_dst.  65536 threads: 4 threads per
// (n,h) over s-quarters, shfl-combine; then shfl over h for the xyz mean.
// ---------------------------------------------------------------------------
__global__ __launch_bounds__(256)
void ms_fin(const float* __restrict__ Pzs,
            float* __restrict__ xyz_dst,
            float* __restrict__ invzb,
            int wlast)
{
    const int gid = blockIdx.x * 256 + threadIdx.x;   // 0..65535
    const int sq = gid & 3;
    const int h  = (gid >> 2) & 7;
    const int n  = gid >> 5;
    const float4* P4 = reinterpret_cast<const float4*>(Pzs);
    float z = 0.f, sx = 0.f, sy = 0.f, sz = 0.f;
#pragma unroll
    for (int s = sq * 16; s < sq * 16 + 16; s++) {
        float4 p = P4[((long)s * 8 + h) * 2048 + n];
        z += p.x; sx += p.y; sy += p.z; sz += p.w;
    }
#pragma unroll
    for (int d = 1; d < 4; d <<= 1) {
        z  += __shfl_xor(z, d, 64);
        sx += __shfl_xor(sx, d, 64);
        sy += __shfl_xor(sy, d, 64);
        sz += __shfl_xor(sz, d, 64);
    }
    const float iz = 1.0f / z;
    if (wlast && sq == 0) invzb[h * 2048 + n] = iz;
    float cx = iz * sx, cy = iz * sy, cz = iz * sz;
#pragma unroll
    for (int d = 4; d < 32; d <<= 1) {
        cx += __shfl_xor(cx, d, 64);
        cy += __shfl_xor(cy, d, 64);
        cz += __shfl_xor(cz, d, 64);
    }
    if ((gid & 31) == 0) {
        xyz_dst[n * 3 + 0] = cx * 0.125f;
        xyz_dst[n * 3 + 1] = cy * 0.125f;
        xyz_dst[n * 3 + 2] = cz * 0.125f;
    }
}

// ---------------------------------------------------------------------------
// g_kern: gbf[n][m] = mask ? bf16(exp(-d2*c2k)*yh[m] + 1e-9) : 0, from the
// last iteration's input xyz.  grid (4 m-chunks, 256 row-tiles of 8).
// ---------------------------------------------------------------------------
__global__ __launch_bounds__(256)
void g_kern(const float* __restrict__ xyz4,
            const float* __restrict__ y_hat,
            const unsigned char* __restrict__ mby,
            const float* __restrict__ bwp,
            unsigned short* __restrict__ gbf)
{
    const int mc = blockIdx.x * 512;
    const int n0 = blockIdx.y * 8;
    const int tid = threadIdx.x;

    __shared__ float sxn[8], syn[8], szn[8], ssn[8];
    if (tid < 8) {
        const float x = xyz4[(n0 + tid) * 3 + 0];
        const float y = xyz4[(n0 + tid) * 3 + 1];
        const float z = xyz4[(n0 + tid) * 3 + 2];
        sxn[tid] = x; syn[tid] = y; szn[tid] = z; ssn[tid] = x*x + y*y + z*z;
    }
    __syncthreads();

    const float bw = bwp[0];
    const float c2k = 1.0f / (2.0f * bw * bw);
    const int m0 = mc + tid * 2;

    const float x0 = xyz4[m0 * 3 + 0], y0 = xyz4[m0 * 3 + 1], z0 = xyz4[m0 * 3 + 2];
    const float x1 = xyz4[m0 * 3 + 3], y1 = xyz4[m0 * 3 + 4], z1 = xyz4[m0 * 3 + 5];
    const float s0 = x0*x0 + y0*y0 + z0*z0;
    const float s1 = x1*x1 + y1*y1 + z1*z1;
    const float yh0 = y_hat[m0], yh1 = y_hat[m0 + 1];

#pragma unroll
    for (int r = 0; r < 8; r++) {
        const float xr = sxn[r], yr = syn[r], zr = szn[r], sr = ssn[r];
        const float d20 = sr + s0 - 2.0f * (xr*x0 + yr*y0 + zr*z0);
        const float d21 = sr + s1 - 2.0f * (xr*x1 + yr*y1 + zr*z1);
        const float g0 = __expf(-d20 * c2k) * yh0 + 1e-9f;
        const float g1 = __expf(-d21 * c2k) * yh1 + 1e-9f;
        const unsigned short mk2 = *reinterpret_cast<const unsigned short*>(
            mby + (long)(n0 + r) * 2048 + m0);
        ushort2 o;
        o.x = (mk2 & 0xff) ? f2bf(g0) : (unsigned short)0;
        o.y = (mk2 >> 8)   ? f2bf(g1) : (unsigned short)0;
        *reinterpret_cast<ushort2*>(gbf + (long)(n0 + r) * 2048 + m0) = o;
    }
}

// ---------------------------------------------------------------------------
// av_mfma: x_partial = (E ⊙ g) @ v, E recomputed in-block via MFMA.
// grid (32 n-tiles, 4 m-splits, 8 heads).  Everything wave-private:
// wave wv owns rows n0+wv*16..+15 of As/gs -> NO barriers in the kt loop.
// Per kt (128 m): stage g rows via global_load_lds, scores via 16 MFMA,
// exp*g -> As (bf16), then 16 MFMA against vT.  fp32 partial planes.
// ---------------------------------------------------------------------------
__global__ __launch_bounds__(256)
void av_mfma(const unsigned short* __restrict__ qh,
             const unsigned short* __restrict__ kh,
             const unsigned short* __restrict__ gbf,  // [2048][2048] (masked)
             const unsigned short* __restrict__ vT,   // [512][2048]
             const float* __restrict__ tptr,
             float* __restrict__ P)                   // [4][2048][512]
{
    const int h  = blockIdx.z;
    const int s  = blockIdx.y;
    const int bx = blockIdx.x;
    const int tid = threadIdx.x;
    const int wv = tid >> 6;
    const int lane = tid & 63;
    const int n0 = bx * 64;
    const int kc = s * 512;
    const int q = lane >> 4;
    const int mcol = lane & 15;
    const int arow = lane & 15;
    const int koct = q * 8;

    __shared__ unsigned short As[64][132];
    __shared__ unsigned short gs[64][128];

    const float scale = 1.0f / (8.0f * tptr[0]);

    const unsigned short* Ap = qh + (long)(n0 + wv * 16 + arow) * 512 + h * 64;
    const bf16x8 aq0 = *reinterpret_cast<const bf16x8*>(Ap + koct);
    const bf16x8 aq1 = *reinterpret_cast<const bf16x8*>(Ap + 32 + koct);

    f32x4 acc[4] = {};
    for (int kt = 0; kt < 4; kt++) {
        const int kb = kc + kt * 128;

        // stage this wave's 16 g-rows (4 KB) -> gs[wv*16..+15][0..127]
#pragma unroll
        for (int i = 0; i < 4; i++) {
            __builtin_amdgcn_global_load_lds(
                (const __attribute__((address_space(1))) unsigned int*)(
                    gbf + (long)(n0 + wv * 16 + i * 4 + (lane >> 4)) * 2048
                        + kb + (lane & 15) * 8),
                (__attribute__((address_space(3))) unsigned int*)&gs[wv * 16 + i * 4][0],
                16, 0, 0);
        }

        // scores for this wave's 16 rows x 128 m
        f32x4 c[8];
#pragma unroll
        for (int mt = 0; mt < 8; mt++) {
            const unsigned short* Bk =
                kh + (long)(kb + mt * 16 + arow) * 512 + h * 64;
            bf16x8 b0 = *reinterpret_cast<const bf16x8*>(Bk + koct);
            bf16x8 b1 = *reinterpret_cast<const bf16x8*>(Bk + 32 + koct);
            f32x4 cc = {};
            cc = __builtin_amdgcn_mfma_f32_16x16x32_bf16(aq0, b0, cc, 0, 0, 0);
            cc = __builtin_amdgcn_mfma_f32_16x16x32_bf16(aq1, b1, cc, 0, 0, 0);
            c[mt] = cc;
        }

        asm volatile("s_waitcnt vmcnt(0)" ::: "memory");  // gs DMA done (wave-private)

#pragma unroll
        for (int mt = 0; mt < 8; mt++)
#pragma unroll
            for (int r = 0; r < 4; r++) {
                const float e = __expf(c[mt][r] * scale);
                const unsigned short gv = gs[wv * 16 + q * 4 + r][mt * 16 + mcol];
                As[wv * 16 + q * 4 + r][mt * 16 + mcol] = f2bf(e * bf2f(gv));
            }

        // As rows are wave-private; compiler orders ds_write->ds_read.
#pragma unroll
        for (int k2 = 0; k2 < 128; k2 += 32) {
            bf16x8 a = *reinterpret_cast<const bf16x8*>(&As[wv * 16 + arow][k2 + koct]);
#pragma unroll
            for (int t = 0; t < 4; t++) {
                bf16x8 b = *reinterpret_cast<const bf16x8*>(
                    vT + ((long)h * 64 + t * 16 + arow) * 2048 + kb + k2 + koct);
                acc[t] = __builtin_amdgcn_mfma_f32_16x16x32_bf16(a, b, acc[t], 0, 0, 0);
            }
        }
    }

    float* Pp = P + (long)s * 1048576;
    const int rbase = n0 + wv * 16 + q * 4;
#pragma unroll
    for (int t = 0; t < 4; t++)
#pragma unroll
        for (int r = 0; r < 4; r++)
            Pp[(long)(rbase + r) * 512 + h * 64 + t * 16 + mcol] = acc[t][r];
}

// ---------------------------------------------------------------------------
// xc[n][d] bf16 = invz_h[n] * sum of 4 fp32 partials. 8 elems/thread.
// ---------------------------------------------------------------------------
__global__ __launch_bounds__(256)
void av_red(const float* __restrict__ P, const float* __restrict__ invzb,
            unsigned short* __restrict__ xc)
{
    const long idx = (long)(blockIdx.x * 256 + threadIdx.x) * 8;
    const int n = (int)(idx >> 9);
    const int d0 = (int)(idx & 511);
    const float iz = invzb[(d0 >> 6) * 2048 + n];
    float s[8] = {};
#pragma unroll
    for (int p = 0; p < 4; p++) {
        const float* pp = P + (long)p * 1048576 + idx;
        float4 a = *reinterpret_cast<const float4*>(pp);
        float4 b = *reinterpret_cast<const float4*>(pp + 4);
        s[0] += a.x; s[1] += a.y; s[2] += a.z; s[3] += a.w;
        s[4] += b.x; s[5] += b.y; s[6] += b.z; s[7] += b.w;
    }
    EU o;
#pragma unroll
    for (int j = 0; j < 8; j++) o.u[j] = f2bf(s[j] * iz);
    *reinterpret_cast<bf16x8*>(xc + idx) = o.v;
}

// ---------------------------------------------------------------------------
// out = xc @ Wo.T + bo via bf16 MFMA, fp32 out. grid (32 n-tiles, 8 d-tiles).
// ---------------------------------------------------------------------------
__global__ __launch_bounds__(256)
void out_mfma(const unsigned short* __restrict__ xc,
              const unsigned short* __restrict__ sW,   // seg 3 = Wo
              const float* __restrict__ bo,
              float* __restrict__ out)
{
    const int bx = blockIdx.x;
    const int by = blockIdx.y;
    const int wv = threadIdx.x >> 6;
    const int lane = threadIdx.x & 63;
    const int row  = lane & 15;
    const int koct = (lane >> 4) * 8;
    const int n0 = bx * 64;

    const unsigned short* Ap = xc + (long)(n0 + wv * 16 + row) * 512;
    const unsigned short* Bp = sW + 3L * 262144 + (long)(by * 64 + row) * 512;

    f32x4 acc[4] = {};
#pragma unroll
    for (int k0 = 0; k0 < 512; k0 += 32) {
        bf16x8 a = *reinterpret_cast<const bf16x8*>(Ap + k0 + koct);
#pragma unroll
        for (int t = 0; t < 4; t++) {
            bf16x8 b = *reinterpret_cast<const bf16x8*>(Bp + (long)(t * 16) * 512 + k0 + koct);
            acc[t] = __builtin_amdgcn_mfma_f32_16x16x32_bf16(a, b, acc[t], 0, 0, 0);
        }
    }

    const int rbase = n0 + wv * 16 + (lane >> 4) * 4;
    const int dcol = lane & 15;
#pragma unroll
    for (int t = 0; t < 4; t++) {
        const int col = by * 64 + t * 16 + dcol;
        const float bb = bo[col];
#pragma unroll
        for (int r = 0; r < 4; r++)
            out[(long)(rbase + r) * 512 + col] = acc[t][r] + bb;
    }
}

// ---------------------------------------------------------------------------
extern "C" void kernel_launch(void* const* d_in, const int* in_sizes, int n_in,
                              void* d_out, int out_size, void* d_ws, size_t ws_size,
                              hipStream_t stream)
{
    (void)in_sizes; (void)n_in; (void)out_size; (void)ws_size;

    const float* xyz   = (const float*)d_in[0];
    const float* strf  = (const float*)d_in[1];
    // d_in[2] esm_feat: dead code (DCE'd in reference)
    const float* yhat  = (const float*)d_in[3];
    const int*   dmask = (const int*)d_in[4];
    const float* tptr  = (const float*)d_in[5];
    const float* bwptr = (const float*)d_in[6];
    // d_in[7] max_iter = 5 (fixed)
    const float* Wq = (const float*)d_in[8];
    const float* bq = (const float*)d_in[9];
    const float* Wk = (const float*)d_in[10];
    const float* bk = (const float*)d_in[11];
    const float* Wv = (const float*)d_in[12];
    const float* bv = (const float*)d_in[13];
    const float* Wo = (const float*)d_in[14];
    const float* bo = (const float*)d_in[15];
    float* outp = (float*)d_out;

    char* wsb = (char*)d_ws;
    float* Ppart         = (float*)(wsb);                        // [4][2048][512] f32, 16 MB
    unsigned short* xc   = (unsigned short*)(wsb + (16L << 20)); // 2 MB
    unsigned short* sA   = (unsigned short*)(wsb + (18L << 20)); // 2 MB
    unsigned short* sW   = (unsigned short*)(wsb + (20L << 20)); // [4][262144] bf16, 2 MB
    unsigned short* qh   = (unsigned short*)(wsb + (22L << 20)); // 2 MB
    unsigned short* kh   = (unsigned short*)(wsb + (24L << 20)); // 2 MB
    unsigned short* vT   = (unsigned short*)(wsb + (26L << 20)); // 2 MB
    float* xyzA          = (float*)(wsb + (28L << 20));
    float* xyzB          = xyzA + 8192;
    unsigned char* mby   = (unsigned char*)(wsb + (30L << 20));  // 4 MB
    float* Pzs           = (float*)(wsb + (34L << 20));          // [64][8][2048][4] f32, 16 MB
    unsigned short* gbf  = (unsigned short*)(wsb + (50L << 20)); // [2048][2048] bf16, 8 MB
    float* invzb         = (float*)(wsb + (58L << 20));          // [8][2048] f32, 64 KB

    dim3 blk(256, 1, 1);

    // bf16 conversions (incl. Wo) + byte mask + q/k/v MFMA projections
    conv_all<<<dim3(3072), blk, 0, stream>>>(strf, Wq, Wk, Wv, Wo, dmask, sA, sW, mby);
    qkv_mfma<<<dim3(32, 8, 3), blk, 0, stream>>>(sA, sW, bq, bk, bv, qh, kh, vT);

    // 5 mean-shift iterations: register-resident fused sweep + slice reduce
    const float* src = xyz;
    float* dsts[5] = {xyzA, xyzB, xyzA, xyzB, outp};
    for (int it = 0; it < 5; it++) {
        ms_swp<<<dim3(64, 16), blk, 0, stream>>>(qh, kh, mby, src, yhat, tptr, bwptr, Pzs);
        ms_fin<<<dim3(256), blk, 0, stream>>>(Pzs, dsts[it], invzb, it == 4 ? 1 : 0);
        src = dsts[it];
    }

    // g (masked) from the LAST iteration's input xyz (= xyzB), then
    // x = (E ⊙ g) @ v with E recomputed in-block, reduce*invz, out-proj
    g_kern<<<dim3(4, 256), blk, 0, stream>>>(xyzB, yhat, mby, bwptr, gbf);
    av_mfma<<<dim3(32, 4, 8), blk, 0, stream>>>(qh, kh, gbf, vT, tptr, Ppart);
    av_red<<<dim3(512), blk, 0, stream>>>(Ppart, invzb, xc);
    out_mfma<<<dim3(32, 8), blk, 0, stream>>>(xc, sW, bo, outp + 6144);
}

// Round 5
// 422.492 us; speedup vs baseline: 1.2124x; 1.0151x over previous
//
#include <hip/hip_runtime.h>

// Problem constants (fixed by setup_inputs): N=2048, D=512, H=8, dh=64, max_iter=5.
// Identity: exp(s/t + log(kern*yw+eps)) = exp(s/(8t)) * (kern*yw+eps).
// R5 architecture: E never materialized; ALL cross-layout moves vectorized.
//  - Swapped score MFMA (A=kh m-rows, B=qh n-cols): lane holds 4 consecutive m
//    for one n. exp*g packed with v_cvt_pk_bf16_f32 -> wave-private LDS
//    exchange (1 ds_write_b128 + 2 ds_read_b64, fixed permutation) yields a
//    legal MFMA B-fragment of EG (bf16).
//  - ms_swp: m-reduction ON THE MATRIX PIPE: C[comp][n] = A * EG^T with
//    A rows {1, xh, xl, yh, yl, zh, zl} (hi/lo bf16 split of coords).
//    Per h: 8 score MFMA + 2 reduce MFMA; no shfl. In-block cross-wave LDS
//    reduce -> Pzs [8][2048][16 slices][2] float4 (8 MB, contiguous reads).
//  - av_mfma: same EG frag feeds PV directly (A = vT staged in swizzled LDS);
//    scalar u16 LDS round-trip + 1M bank conflicts deleted.

typedef __attribute__((ext_vector_type(8))) short bf16x8;
typedef __attribute__((ext_vector_type(4))) float f32x4;

__device__ __forceinline__ unsigned short f2bf(float f) {
    unsigned int u = __float_as_uint(f);
    u += 0x7fff + ((u >> 16) & 1);   // RNE (inputs finite)
    return (unsigned short)(u >> 16);
}
__device__ __forceinline__ float bf2f(unsigned short u) {
    return __uint_as_float((unsigned int)u << 16);
}
__device__ __forceinline__ unsigned int cvtpk(float lo, float hi) {
    unsigned int r;
    asm volatile("v_cvt_pk_bf16_f32 %0, %1, %2" : "=v"(r) : "v"(lo), "v"(hi));
    return r;
}

union EU { bf16x8 v; unsigned short u[8]; };

// ---------------------------------------------------------------------------
// Convert strf + Wq/Wk/Wv/Wo fp32->bf16 (sW = [4][262144]) and dmask->byte.
// ---------------------------------------------------------------------------
__global__ __launch_bounds__(256)
void conv_all(const float* __restrict__ strf,
              const float* __restrict__ Wq, const float* __restrict__ Wk,
              const float* __restrict__ Wv, const float* __restrict__ Wo,
              const int* __restrict__ dmask,
              unsigned short* __restrict__ sA, unsigned short* __restrict__ sW,
              unsigned char* __restrict__ mby)
{
    const long base = (long)(blockIdx.x * 256 + threadIdx.x) * 8;
    if (base >= 2097152) {
        const long rel = base - 2097152;
        int4 a = *reinterpret_cast<const int4*>(dmask + rel);
        int4 b = *reinterpret_cast<const int4*>(dmask + rel + 4);
        unsigned long long p = 0;
        p |= (a.x > 0) ? 0x01ULL : 0;  p |= (a.y > 0) ? 0x0100ULL : 0;
        p |= (a.z > 0) ? 0x010000ULL : 0;  p |= (a.w > 0) ? 0x01000000ULL : 0;
        p |= (b.x > 0) ? 0x0100000000ULL : 0;  p |= (b.y > 0) ? 0x010000000000ULL : 0;
        p |= (b.z > 0) ? 0x01000000000000ULL : 0;  p |= (b.w > 0) ? 0x0100000000000000ULL : 0;
        *reinterpret_cast<unsigned long long*>(mby + rel) = p;
        return;
    }
    const float* src;
    unsigned short* dst;
    if (base < 1048576) {
        src = strf + base; dst = sA + base;
    } else {
        const long rel = base - 1048576;
        const int seg = (int)(rel >> 18);
        const long off = rel & 262143;
        const float* Ws[4] = {Wq, Wk, Wv, Wo};
        src = Ws[seg] + off;
        dst = sW + (long)seg * 262144 + off;
    }
    float4 a = *reinterpret_cast<const float4*>(src);
    float4 b = *reinterpret_cast<const float4*>(src + 4);
    EU o;
    o.u[0] = f2bf(a.x); o.u[1] = f2bf(a.y); o.u[2] = f2bf(a.z); o.u[3] = f2bf(a.w);
    o.u[4] = f2bf(b.x); o.u[5] = f2bf(b.y); o.u[6] = f2bf(b.z); o.u[7] = f2bf(b.w);
    *reinterpret_cast<bf16x8*>(dst) = o.v;
}

// ---------------------------------------------------------------------------
// q/k/v projection via bf16 MFMA. grid (32 n-tiles, 8 d-tiles, 3).
// ---------------------------------------------------------------------------
__global__ __launch_bounds__(256)
void qkv_mfma(const unsigned short* __restrict__ sA,
              const unsigned short* __restrict__ sW,
              const float* __restrict__ bq, const float* __restrict__ bk,
              const float* __restrict__ bv,
              unsigned short* __restrict__ qh, unsigned short* __restrict__ kh,
              unsigned short* __restrict__ vT)
{
    const int z  = blockIdx.z;
    const int bx = blockIdx.x;
    const int by = blockIdx.y;
    const int tid = threadIdx.x;
    const int wv = tid >> 6;
    const int lane = tid & 63;
    const int row  = lane & 15;
    const int koct = (lane >> 4) * 8;
    const int n0 = bx * 64;

    const unsigned short* Ap = sA + (long)(n0 + wv * 16 + row) * 512;
    const unsigned short* Bp = sW + (long)z * 262144 + (long)(by * 64 + row) * 512;

    f32x4 acc[4] = {};
#pragma unroll
    for (int k0 = 0; k0 < 512; k0 += 32) {
        bf16x8 a = *reinterpret_cast<const bf16x8*>(Ap + k0 + koct);
#pragma unroll
        for (int t = 0; t < 4; t++) {
            bf16x8 b = *reinterpret_cast<const bf16x8*>(Bp + (long)(t * 16) * 512 + k0 + koct);
            acc[t] = __builtin_amdgcn_mfma_f32_16x16x32_bf16(a, b, acc[t], 0, 0, 0);
        }
    }

    if (z == 2) {
        const int rbase = n0 + wv * 16 + (lane >> 4) * 4;
#pragma unroll
        for (int t = 0; t < 4; t++) {
            const int d = by * 64 + t * 16 + (lane & 15);
            const float bb = bv[d];
            ushort4 o;
            o.x = f2bf(acc[t][0] + bb); o.y = f2bf(acc[t][1] + bb);
            o.z = f2bf(acc[t][2] + bb); o.w = f2bf(acc[t][3] + bb);
            *reinterpret_cast<ushort4*>(vT + (long)d * 2048 + rbase) = o;
        }
        return;
    }

    __shared__ float ls[64][68];
    const int lrb = wv * 16 + (lane >> 4) * 4;
    const int lcb = lane & 15;
#pragma unroll
    for (int t = 0; t < 4; t++)
#pragma unroll
        for (int r = 0; r < 4; r++)
            ls[lrb + r][t * 16 + lcb] = acc[t][r];
    __syncthreads();

    const float* bias = (z == 0) ? bq : bk;
    unsigned short* dst = (z == 0) ? qh : kh;
    const int r2 = tid >> 2;
    const int c2 = (tid & 3) * 16;
    float sv[16];
#pragma unroll
    for (int j = 0; j < 4; j++) {
        float4 s = *reinterpret_cast<const float4*>(&ls[r2][c2 + j * 4]);
        float4 bb = *reinterpret_cast<const float4*>(bias + by * 64 + c2 + j * 4);
        sv[j*4+0] = s.x + bb.x; sv[j*4+1] = s.y + bb.y;
        sv[j*4+2] = s.z + bb.z; sv[j*4+3] = s.w + bb.w;
    }
    EU o0, o1;
#pragma unroll
    for (int j = 0; j < 8; j++) { o0.u[j] = f2bf(sv[j]); o1.u[j] = f2bf(sv[8 + j]); }
    unsigned short* dp = dst + (long)(n0 + r2) * 512 + by * 64 + c2;
    *reinterpret_cast<bf16x8*>(dp)     = o0.v;
    *reinterpret_cast<bf16x8*>(dp + 8) = o1.v;
}

// ---------------------------------------------------------------------------
// ms_swp: one mean-shift sweep. grid (64 n-tiles of 32, 16 m-splits of 128);
// block 256 = 4 waves, wave owns 32 consecutive m. Swapped score MFMA ->
// EG B-frag via cvt_pk + LDS exchange -> reduce MFMA with A rows
// {1,xh,xl,yh,yl,zh,zl}. Per-h results to LDS; cross-wave reduce -> Pzs.
// ---------------------------------------------------------------------------
__global__ __launch_bounds__(256)
void ms_swp(const unsigned short* __restrict__ qh,
            const unsigned short* __restrict__ kh,
            const unsigned char* __restrict__ mby,
            const float* __restrict__ xyz_src,
            const float* __restrict__ y_hat,
            const float* __restrict__ tptr,
            const float* __restrict__ bwp,
            float* __restrict__ Pzs)        // [8][2048][16][2] float4 = 8 MB
{
    const int n0 = blockIdx.x * 32;
    const int tid = threadIdx.x;
    const int wv = tid >> 6;
    const int lane = tid & 63;
    const int fr = lane & 15;
    const int g  = lane >> 4;
    const int koct = g * 8;
    const int mc = blockIdx.y * 128 + wv * 32;

    __shared__ unsigned int exsc[4][64][4];          // 4 KB exchange scratch
    __shared__ float4 red[4][8][2][16][2];           // 32 KB per-h partials

    const float scale = 1.0f / (8.0f * tptr[0]);
    const float bw = bwp[0];
    const float c2k = 1.0f / (2.0f * bw * bw);

    // n-side scalars (two 16-n subtiles)
    float xn[2], yn[2], zn[2], sqn[2];
#pragma unroll
    for (int ns = 0; ns < 2; ns++) {
        const int n = n0 + ns * 16 + fr;
        const float x = xyz_src[n * 3 + 0];
        const float y = xyz_src[n * 3 + 1];
        const float z = xyz_src[n * 3 + 2];
        xn[ns] = x; yn[ns] = y; zn[ns] = z; sqn[ns] = x*x + y*y + z*z;
    }

    // masked g per (ns, m-offset 4g+r within tile t)
    float gm[2][8];
#pragma unroll
    for (int t = 0; t < 2; t++) {
        const int m0 = mc + t * 16 + g * 4;
        const float4 p0 = *reinterpret_cast<const float4*>(xyz_src + m0 * 3);
        const float4 p1 = *reinterpret_cast<const float4*>(xyz_src + m0 * 3 + 4);
        const float4 p2 = *reinterpret_cast<const float4*>(xyz_src + m0 * 3 + 8);
        const float mx[4] = {p0.x, p0.w, p1.z, p2.y};
        const float my[4] = {p0.y, p1.x, p1.w, p2.z};
        const float mz[4] = {p0.z, p1.y, p2.x, p2.w};
        const float4 yh4 = *reinterpret_cast<const float4*>(y_hat + m0);
        const float yhv[4] = {yh4.x, yh4.y, yh4.z, yh4.w};
        unsigned int mk[2];
        mk[0] = *reinterpret_cast<const unsigned int*>(mby + (long)(n0 + fr) * 2048 + m0);
        mk[1] = *reinterpret_cast<const unsigned int*>(mby + (long)(n0 + 16 + fr) * 2048 + m0);
#pragma unroll
        for (int r = 0; r < 4; r++) {
            const float sm = mx[r]*mx[r] + my[r]*my[r] + mz[r]*mz[r];
#pragma unroll
            for (int ns = 0; ns < 2; ns++) {
                const float d2 = sqn[ns] + sm
                               - 2.0f * (xn[ns]*mx[r] + yn[ns]*my[r] + zn[ns]*mz[r]);
                const float gv = __expf(-d2 * c2k) * yhv[r] + 1e-9f;
                gm[ns][t*4+r] = ((mk[ns] >> (8*r)) & 0xffu) ? gv : 0.0f;
            }
        }
    }

    // A-frag: rows {1, xh, xl, yh, yl, zh, zl, 0..}, k = m-offset 8g+jj
    EU ab;
    {
        const float* xp = xyz_src + (long)(mc + 8 * g) * 3;
        float qv[24];
#pragma unroll
        for (int i = 0; i < 6; i++)
            *reinterpret_cast<float4*>(&qv[i*4]) =
                *reinterpret_cast<const float4*>(xp + i*4);
#pragma unroll
        for (int jj = 0; jj < 8; jj++) {
            const float vx = qv[jj*3+0], vy = qv[jj*3+1], vz = qv[jj*3+2];
            const float cv = (fr < 3) ? vx : (fr < 5) ? vy : vz;
            const unsigned short hi = f2bf(cv);
            const unsigned short lo = f2bf(cv - bf2f(hi));
            unsigned short ov = (fr & 1) ? hi : lo;
            if (fr == 0) ov = 0x3F80;      // bf16 1.0
            if (fr >= 7) ov = 0;
            ab.u[jj] = ov;
        }
    }

    // exchange permutation (fixed per lane)
    const int la = (((2 * g) & 3) << 4) + fr;
    const int lb = (((2 * g + 1) & 3) << 4) + fr;
    const int ts = (g >> 1) * 2;

#pragma unroll 2
    for (int h = 0; h < 8; h++) {
        bf16x8 a0[2], a1[2], b0[2], b1[2];
#pragma unroll
        for (int t = 0; t < 2; t++) {
            const unsigned short* Ap = kh + (long)(mc + t * 16 + fr) * 512 + h * 64;
            a0[t] = *reinterpret_cast<const bf16x8*>(Ap + koct);
            a1[t] = *reinterpret_cast<const bf16x8*>(Ap + 32 + koct);
        }
#pragma unroll
        for (int ns = 0; ns < 2; ns++) {
            const unsigned short* Bp = qh + (long)(n0 + ns * 16 + fr) * 512 + h * 64;
            b0[ns] = *reinterpret_cast<const bf16x8*>(Bp + koct);
            b1[ns] = *reinterpret_cast<const bf16x8*>(Bp + 32 + koct);
        }
        f32x4 c[2][2];
#pragma unroll
        for (int t = 0; t < 2; t++)
#pragma unroll
            for (int ns = 0; ns < 2; ns++) {
                f32x4 cc = {};
                cc = __builtin_amdgcn_mfma_f32_16x16x32_bf16(a0[t], b0[ns], cc, 0, 0, 0);
                cc = __builtin_amdgcn_mfma_f32_16x16x32_bf16(a1[t], b1[ns], cc, 0, 0, 0);
                c[t][ns] = cc;
            }
#pragma unroll
        for (int ns = 0; ns < 2; ns++) {
            float e[8];
#pragma unroll
            for (int t = 0; t < 2; t++)
#pragma unroll
                for (int r = 0; r < 4; r++)
                    e[t*4+r] = __expf(c[t][ns][r] * scale) * gm[ns][t*4+r];
            const unsigned int P0 = cvtpk(e[0], e[1]);
            const unsigned int P1 = cvtpk(e[2], e[3]);
            const unsigned int Q0 = cvtpk(e[4], e[5]);
            const unsigned int Q1 = cvtpk(e[6], e[7]);
            *reinterpret_cast<int4*>(&exsc[wv][lane][0]) =
                make_int4((int)P0, (int)P1, (int)Q0, (int)Q1);
            const uint2 d01 = *reinterpret_cast<const uint2*>(&exsc[wv][la][ts]);
            const uint2 d23 = *reinterpret_cast<const uint2*>(&exsc[wv][lb][ts]);
            union { int4 i; bf16x8 v; } fb;
            fb.i = make_int4((int)d01.x, (int)d01.y, (int)d23.x, (int)d23.y);
            f32x4 cc = {};
            cc = __builtin_amdgcn_mfma_f32_16x16x32_bf16(ab.v, fb.v, cc, 0, 0, 0);
            if (g < 2)
                red[wv][h][ns][fr][g] = make_float4(cc[0], cc[1], cc[2], cc[3]);
        }
    }
    __syncthreads();

    // cross-wave reduce: 512 items, 2 per thread -> Pzs[h][n][slice][g]
#pragma unroll
    for (int it = 0; it < 2; it++) {
        const int idx = tid * 2 + it;
        const int gg = idx & 1;
        const int f2 = (idx >> 1) & 15;
        const int n2 = (idx >> 5) & 1;
        const int h2 = idx >> 6;
        float4 s0 = red[0][h2][n2][f2][gg];
        float4 s1 = red[1][h2][n2][f2][gg];
        float4 s2 = red[2][h2][n2][f2][gg];
        float4 s3 = red[3][h2][n2][f2][gg];
        float4 o = make_float4(s0.x+s1.x+s2.x+s3.x, s0.y+s1.y+s2.y+s3.y,
                               s0.z+s1.z+s2.z+s3.z, s0.w+s1.w+s2.w+s3.w);
        reinterpret_cast<float4*>(Pzs)[
            (((long)h2 * 2048 + n0 + n2 * 16 + f2) * 16 + blockIdx.y) * 2 + gg] = o;
    }
}

// ---------------------------------------------------------------------------
// ms_fin: per (n,h): sum 16 slices (512 B contiguous), invz, xyz mean.
// 16384 threads, grid 128x128.
// ---------------------------------------------------------------------------
__global__ __launch_bounds__(128)
void ms_fin(const float* __restrict__ Pzs,
            float* __restrict__ xyz_dst,
            float* __restrict__ invzb,
            int wlast)
{
    const int gid = blockIdx.x * 128 + threadIdx.x;   // 0..16383
    const int n = gid >> 3;
    const int h = gid & 7;
    const float4* P4 = reinterpret_cast<const float4*>(Pzs) + ((long)h * 2048 + n) * 32;
    float z = 0.f, sxh = 0.f, sxl = 0.f, syh = 0.f, syl = 0.f, szh = 0.f, szl = 0.f;
#pragma unroll
    for (int s = 0; s < 16; s++) {
        const float4 p0 = P4[s * 2];
        const float4 p1 = P4[s * 2 + 1];
        z += p0.x; sxh += p0.y; sxl += p0.z; syh += p0.w;
        syl += p1.x; szh += p1.y; szl += p1.z;
    }
    const float iz = 1.0f / z;
    if (wlast) invzb[h * 2048 + n] = iz;
    float cx = iz * (sxh + sxl);
    float cy = iz * (syh + syl);
    float cz = iz * (szh + szl);
#pragma unroll
    for (int d = 1; d < 8; d <<= 1) {
        cx += __shfl_xor(cx, d, 64);
        cy += __shfl_xor(cy, d, 64);
        cz += __shfl_xor(cz, d, 64);
    }
    if (h == 0) {
        xyz_dst[n * 3 + 0] = cx * 0.125f;
        xyz_dst[n * 3 + 1] = cy * 0.125f;
        xyz_dst[n * 3 + 2] = cz * 0.125f;
    }
}

// ---------------------------------------------------------------------------
// g_kern: gbf[n][m] = mask ? bf16(exp(-d2*c2k)*yh[m] + 1e-9) : 0.
// ---------------------------------------------------------------------------
__global__ __launch_bounds__(256)
void g_kern(const float* __restrict__ xyz4,
            const float* __restrict__ y_hat,
            const unsigned char* __restrict__ mby,
            const float* __restrict__ bwp,
            unsigned short* __restrict__ gbf)
{
    const int mc = blockIdx.x * 512;
    const int n0 = blockIdx.y * 8;
    const int tid = threadIdx.x;

    __shared__ float sxn[8], syn[8], szn[8], ssn[8];
    if (tid < 8) {
        const float x = xyz4[(n0 + tid) * 3 + 0];
        const float y = xyz4[(n0 + tid) * 3 + 1];
        const float z = xyz4[(n0 + tid) * 3 + 2];
        sxn[tid] = x; syn[tid] = y; szn[tid] = z; ssn[tid] = x*x + y*y + z*z;
    }
    __syncthreads();

    const float bw = bwp[0];
    const float c2k = 1.0f / (2.0f * bw * bw);
    const int m0 = mc + tid * 2;

    const float x0 = xyz4[m0 * 3 + 0], y0 = xyz4[m0 * 3 + 1], z0 = xyz4[m0 * 3 + 2];
    const float x1 = xyz4[m0 * 3 + 3], y1 = xyz4[m0 * 3 + 4], z1 = xyz4[m0 * 3 + 5];
    const float s0 = x0*x0 + y0*y0 + z0*z0;
    const float s1 = x1*x1 + y1*y1 + z1*z1;
    const float yh0 = y_hat[m0], yh1 = y_hat[m0 + 1];

#pragma unroll
    for (int r = 0; r < 8; r++) {
        const float xr = sxn[r], yr = syn[r], zr = szn[r], sr = ssn[r];
        const float d20 = sr + s0 - 2.0f * (xr*x0 + yr*y0 + zr*z0);
        const float d21 = sr + s1 - 2.0f * (xr*x1 + yr*y1 + zr*z1);
        const float g0 = __expf(-d20 * c2k) * yh0 + 1e-9f;
        const float g1 = __expf(-d21 * c2k) * yh1 + 1e-9f;
        const unsigned short mk2 = *reinterpret_cast<const unsigned short*>(
            mby + (long)(n0 + r) * 2048 + m0);
        ushort2 o;
        o.x = (mk2 & 0xff) ? f2bf(g0) : (unsigned short)0;
        o.y = (mk2 >> 8)   ? f2bf(g1) : (unsigned short)0;
        *reinterpret_cast<ushort2*>(gbf + (long)(n0 + r) * 2048 + m0) = o;
    }
}

// ---------------------------------------------------------------------------
// av_mfma: X = (E⊙g) @ v, E recomputed. grid (32 n-tiles of 64, 4 m-splits,
// 8 heads); wave = one 16-n subtile. vT staged per 128-m group into swizzled
// LDS. Score swapped -> EG frag via cvt_pk + LDS exchange -> PV MFMA
// (A = vT rows d, B = EG). No scalar LDS, no conflicts.
// ---------------------------------------------------------------------------
__global__ __launch_bounds__(256)
void av_mfma(const unsigned short* __restrict__ qh,
             const unsigned short* __restrict__ kh,
             const unsigned short* __restrict__ gbf,  // [2048][2048] masked
             const unsigned short* __restrict__ vT,   // [512][2048]
             const float* __restrict__ tptr,
             float* __restrict__ P)                   // [4][2048][512]
{
    const int h  = blockIdx.z;
    const int s  = blockIdx.y;
    const int bx = blockIdx.x;
    const int tid = threadIdx.x;
    const int wv = tid >> 6;
    const int lane = tid & 63;
    const int fr = lane & 15;
    const int g  = lane >> 4;
    const int koct = g * 8;
    const int n0 = bx * 64;

    __shared__ unsigned short vts[8192];      // [64 d][128 m] swizzled, 16 KB
    __shared__ unsigned int exsc[4][64][4];   // 4 KB

    const float scale = 1.0f / (8.0f * tptr[0]);

    const unsigned short* Bp = qh + (long)(n0 + wv * 16 + fr) * 512 + h * 64;
    const bf16x8 b0 = *reinterpret_cast<const bf16x8*>(Bp + koct);
    const bf16x8 b1 = *reinterpret_cast<const bf16x8*>(Bp + 32 + koct);

    const int la = (((2 * g) & 3) << 4) + fr;
    const int lb = (((2 * g + 1) & 3) << 4) + fr;
    const int ts = (g >> 1) * 2;

    const unsigned short* grow = gbf + (long)(n0 + wv * 16 + fr) * 2048;

    f32x4 acc[4] = {};
    for (int grp = 0; grp < 4; grp++) {
        __syncthreads();
        // stage vT[h][0..63][s*512+grp*128 ..+128) -> swizzled LDS (16 KB)
#pragma unroll
        for (int i = 0; i < 4; i++) {
            const int bo = tid * 16 + i * 4096;
            const int row = bo >> 8;
            const int swz = bo ^ ((row & 7) << 4);
            const bf16x8 v = *reinterpret_cast<const bf16x8*>(
                vT + ((long)h * 64 + row) * 2048 + s * 512 + grp * 128 + ((bo & 255) >> 1));
            *reinterpret_cast<bf16x8*>(reinterpret_cast<char*>(vts) + swz) = v;
        }
        __syncthreads();
#pragma unroll
        for (int mblk = 0; mblk < 4; mblk++) {
            const int m0 = s * 512 + grp * 128 + mblk * 32;
            f32x4 c[2];
#pragma unroll
            for (int t = 0; t < 2; t++) {
                const unsigned short* Ap = kh + (long)(m0 + t * 16 + fr) * 512 + h * 64;
                f32x4 cc = {};
                cc = __builtin_amdgcn_mfma_f32_16x16x32_bf16(
                    *reinterpret_cast<const bf16x8*>(Ap + koct), b0, cc, 0, 0, 0);
                cc = __builtin_amdgcn_mfma_f32_16x16x32_bf16(
                    *reinterpret_cast<const bf16x8*>(Ap + 32 + koct), b1, cc, 0, 0, 0);
                c[t] = cc;
            }
            const ushort4 g0 = *reinterpret_cast<const ushort4*>(grow + m0 + 4 * g);
            const ushort4 g1 = *reinterpret_cast<const ushort4*>(grow + m0 + 16 + 4 * g);
            const unsigned int P0 = cvtpk(__expf(c[0][0]*scale)*bf2f(g0.x),
                                          __expf(c[0][1]*scale)*bf2f(g0.y));
            const unsigned int P1 = cvtpk(__expf(c[0][2]*scale)*bf2f(g0.z),
                                          __expf(c[0][3]*scale)*bf2f(g0.w));
            const unsigned int Q0 = cvtpk(__expf(c[1][0]*scale)*bf2f(g1.x),
                                          __expf(c[1][1]*scale)*bf2f(g1.y));
            const unsigned int Q1 = cvtpk(__expf(c[1][2]*scale)*bf2f(g1.z),
                                          __expf(c[1][3]*scale)*bf2f(g1.w));
            *reinterpret_cast<int4*>(&exsc[wv][lane][0]) =
                make_int4((int)P0, (int)P1, (int)Q0, (int)Q1);
            const uint2 d01 = *reinterpret_cast<const uint2*>(&exsc[wv][la][ts]);
            const uint2 d23 = *reinterpret_cast<const uint2*>(&exsc[wv][lb][ts]);
            union { int4 i; bf16x8 v; } fb;
            fb.i = make_int4((int)d01.x, (int)d01.y, (int)d23.x, (int)d23.y);
#pragma unroll
            for (int dt = 0; dt < 4; dt++) {
                const int bofs = (((dt * 16 + fr) << 8) + mblk * 64 + g * 16)
                               ^ ((fr & 7) << 4);
                const bf16x8 avt = *reinterpret_cast<const bf16x8*>(
                    reinterpret_cast<const char*>(vts) + bofs);
                acc[dt] = __builtin_amdgcn_mfma_f32_16x16x32_bf16(avt, fb.v, acc[dt], 0, 0, 0);
            }
        }
    }

    float* Pp = P + (long)s * 1048576;
#pragma unroll
    for (int dt = 0; dt < 4; dt++)
        *reinterpret_cast<float4*>(
            &Pp[(long)(n0 + wv * 16 + fr) * 512 + h * 64 + dt * 16 + 4 * g]) =
            *reinterpret_cast<const float4*>(&acc[dt]);
}

// ---------------------------------------------------------------------------
// xc[n][d] bf16 = invz_h[n] * sum of 4 fp32 partials. 8 elems/thread.
// ---------------------------------------------------------------------------
__global__ __launch_bounds__(256)
void av_red(const float* __restrict__ P, const float* __restrict__ invzb,
            unsigned short* __restrict__ xc)
{
    const long idx = (long)(blockIdx.x * 256 + threadIdx.x) * 8;
    const int n = (int)(idx >> 9);
    const int d0 = (int)(idx & 511);
    const float iz = invzb[(d0 >> 6) * 2048 + n];
    float s[8] = {};
#pragma unroll
    for (int p = 0; p < 4; p++) {
        const float* pp = P + (long)p * 1048576 + idx;
        float4 a = *reinterpret_cast<const float4*>(pp);
        float4 b = *reinterpret_cast<const float4*>(pp + 4);
        s[0] += a.x; s[1] += a.y; s[2] += a.z; s[3] += a.w;
        s[4] += b.x; s[5] += b.y; s[6] += b.z; s[7] += b.w;
    }
    EU o;
#pragma unroll
    for (int j = 0; j < 8; j++) o.u[j] = f2bf(s[j] * iz);
    *reinterpret_cast<bf16x8*>(xc + idx) = o.v;
}

// ---------------------------------------------------------------------------
// out = xc @ Wo.T + bo via bf16 MFMA, fp32 out. grid (32 n-tiles, 8 d-tiles).
// ---------------------------------------------------------------------------
__global__ __launch_bounds__(256)
void out_mfma(const unsigned short* __restrict__ xc,
              const unsigned short* __restrict__ sW,   // seg 3 = Wo
              const float* __restrict__ bo,
              float* __restrict__ out)
{
    const int bx = blockIdx.x;
    const int by = blockIdx.y;
    const int wv = threadIdx.x >> 6;
    const int lane = threadIdx.x & 63;
    const int row  = lane & 15;
    const int koct = (lane >> 4) * 8;
    const int n0 = bx * 64;

    const unsigned short* Ap = xc + (long)(n0 + wv * 16 + row) * 512;
    const unsigned short* Bp = sW + 3L * 262144 + (long)(by * 64 + row) * 512;

    f32x4 acc[4] = {};
#pragma unroll
    for (int k0 = 0; k0 < 512; k0 += 32) {
        bf16x8 a = *reinterpret_cast<const bf16x8*>(Ap + k0 + koct);
#pragma unroll
        for (int t = 0; t < 4; t++) {
            bf16x8 b = *reinterpret_cast<const bf16x8*>(Bp + (long)(t * 16) * 512 + k0 + koct);
            acc[t] = __builtin_amdgcn_mfma_f32_16x16x32_bf16(a, b, acc[t], 0, 0, 0);
        }
    }

    const int rbase = n0 + wv * 16 + (lane >> 4) * 4;
    const int dcol = lane & 15;
#pragma unroll
    for (int t = 0; t < 4; t++) {
        const int col = by * 64 + t * 16 + dcol;
        const float bb = bo[col];
#pragma unroll
        for (int r = 0; r < 4; r++)
            out[(long)(rbase + r) * 512 + col] = acc[t][r] + bb;
    }
}

// ---------------------------------------------------------------------------
extern "C" void kernel_launch(void* const* d_in, const int* in_sizes, int n_in,
                              void* d_out, int out_size, void* d_ws, size_t ws_size,
                              hipStream_t stream)
{
    (void)in_sizes; (void)n_in; (void)out_size; (void)ws_size;

    const float* xyz   = (const float*)d_in[0];
    const float* strf  = (const float*)d_in[1];
    // d_in[2] esm_feat: dead code (DCE'd in reference)
    const float* yhat  = (const float*)d_in[3];
    const int*   dmask = (const int*)d_in[4];
    const float* tptr  = (const float*)d_in[5];
    const float* bwptr = (const float*)d_in[6];
    // d_in[7] max_iter = 5 (fixed)
    const float* Wq = (const float*)d_in[8];
    const float* bq = (const float*)d_in[9];
    const float* Wk = (const float*)d_in[10];
    const float* bk = (const float*)d_in[11];
    const float* Wv = (const float*)d_in[12];
    const float* bv = (const float*)d_in[13];
    const float* Wo = (const float*)d_in[14];
    const float* bo = (const float*)d_in[15];
    float* outp = (float*)d_out;

    char* wsb = (char*)d_ws;
    float* Ppart         = (float*)(wsb);                        // 16 MB
    unsigned short* xc   = (unsigned short*)(wsb + (16L << 20)); // 2 MB
    unsigned short* sA   = (unsigned short*)(wsb + (18L << 20)); // 2 MB
    unsigned short* sW   = (unsigned short*)(wsb + (20L << 20)); // 2 MB
    unsigned short* qh   = (unsigned short*)(wsb + (22L << 20)); // 2 MB
    unsigned short* kh   = (unsigned short*)(wsb + (24L << 20)); // 2 MB
    unsigned short* vT   = (unsigned short*)(wsb + (26L << 20)); // 2 MB
    float* xyzA          = (float*)(wsb + (28L << 20));
    float* xyzB          = xyzA + 8192;
    unsigned char* mby   = (unsigned char*)(wsb + (30L << 20));  // 4 MB
    float* Pzs           = (float*)(wsb + (34L << 20));          // [8][2048][16][2]f4, 8 MB
    unsigned short* gbf  = (unsigned short*)(wsb + (50L << 20)); // 8 MB
    float* invzb         = (float*)(wsb + (58L << 20));          // 64 KB

    dim3 blk(256, 1, 1);

    conv_all<<<dim3(3072), blk, 0, stream>>>(strf, Wq, Wk, Wv, Wo, dmask, sA, sW, mby);
    qkv_mfma<<<dim3(32, 8, 3), blk, 0, stream>>>(sA, sW, bq, bk, bv, qh, kh, vT);

    // 5 mean-shift iterations: MFMA-reduced fused sweep + tiny slice reduce
    const float* src = xyz;
    float* dsts[5] = {xyzA, xyzB, xyzA, xyzB, outp};
    for (int it = 0; it < 5; it++) {
        ms_swp<<<dim3(64, 16), blk, 0, stream>>>(qh, kh, mby, src, yhat, tptr, bwptr, Pzs);
        ms_fin<<<dim3(128), dim3(128), 0, stream>>>(Pzs, dsts[it], invzb, it == 4 ? 1 : 0);
        src = dsts[it];
    }

    g_kern<<<dim3(4, 256), blk, 0, stream>>>(xyzB, yhat, mby, bwptr, gbf);
    av_mfma<<<dim3(32, 4, 8), blk, 0, stream>>>(qh, kh, gbf, vT, tptr, Ppart);
    av_red<<<dim3(512), blk, 0, stream>>>(Ppart, invzb, xc);
    out_mfma<<<dim3(32, 8), blk, 0, stream>>>(xc, sW, bo, outp + 6144);
}

// Round 7
// 402.629 us; speedup vs baseline: 1.2723x; 1.0493x over previous
//
#include <hip/hip_runtime.h>

// Problem constants (fixed by setup_inputs): N=2048, D=512, H=8, dh=64, max_iter=5.
// Identity: exp(s/t + log(kern*yw+eps)) = exp(s/(8t)) * (kern*yw+eps).
// R7 = R5 (last passing) with two surgical changes targeting R5's measured
// 1.57M LDS bank conflicts + strand serialization in the EG exchange:
//  1. The fixed-permutation exchange (score quad -> K=32 B-frag) is done with
//     8 __shfl + 4 selects (ds_bpermute crossbar, conflict-free, no
//     write->read lgkmcnt chain) instead of exsc LDS. Values byte-identical
//     to R5's verified exchange. Applied in ms_swp AND av_mfma.
//  2. av_mfma stages kh (16 KB/grp) into XOR-swizzled LDS exactly like the
//     R5-verified vts stage: kills the 4x-redundant scattered kh L2 reads.
// No new MFMA variants (R6's mfma16 NaN lesson): K=32 MFMA + cvtpk + shfl
// + the R5 swizzle pattern only.

typedef __attribute__((ext_vector_type(8))) short bf16x8;
typedef __attribute__((ext_vector_type(4))) float f32x4;

__device__ __forceinline__ unsigned short f2bf(float f) {
    unsigned int u = __float_as_uint(f);
    u += 0x7fff + ((u >> 16) & 1);   // RNE (inputs finite)
    return (unsigned short)(u >> 16);
}
__device__ __forceinline__ float bf2f(unsigned short u) {
    return __uint_as_float((unsigned int)u << 16);
}
__device__ __forceinline__ unsigned int cvtpk(float lo, float hi) {
    unsigned int r;
    asm volatile("v_cvt_pk_bf16_f32 %0, %1, %2" : "=v"(r) : "v"(lo), "v"(hi));
    return r;
}

union EU { bf16x8 v; unsigned short u[8]; };

// shfl-based EG exchange: dest lane (g,fr) gets the K=32 B-frag dwords from
// lanes srcA=(g&1)*32+fr (dwords 0-1) and srcB=srcA+16 (dwords 2-3), pair
// selected by g>>1 (P-pair for g<2, Q-pair for g>=2). Identical values to
// R5's exsc exchange (la=((2g)&3)*16+fr, lb, ts=(g>>1)*2).
__device__ __forceinline__ bf16x8 eg_exchange(unsigned int P0, unsigned int P1,
                                              unsigned int Q0, unsigned int Q1,
                                              int g, int fr) {
    const int srcA = (g & 1) * 32 + fr;
    const int srcB = srcA + 16;
    const bool selQ = (g >> 1) != 0;
    const unsigned int a0 = (unsigned int)__shfl((int)P0, srcA, 64);
    const unsigned int a1 = (unsigned int)__shfl((int)P1, srcA, 64);
    const unsigned int a2 = (unsigned int)__shfl((int)Q0, srcA, 64);
    const unsigned int a3 = (unsigned int)__shfl((int)Q1, srcA, 64);
    const unsigned int b0 = (unsigned int)__shfl((int)P0, srcB, 64);
    const unsigned int b1 = (unsigned int)__shfl((int)P1, srcB, 64);
    const unsigned int b2 = (unsigned int)__shfl((int)Q0, srcB, 64);
    const unsigned int b3 = (unsigned int)__shfl((int)Q1, srcB, 64);
    union { int4 i; bf16x8 v; } fb;
    fb.i = make_int4((int)(selQ ? a2 : a0), (int)(selQ ? a3 : a1),
                     (int)(selQ ? b2 : b0), (int)(selQ ? b3 : b1));
    return fb.v;
}

// ---------------------------------------------------------------------------
// Convert strf + Wq/Wk/Wv/Wo fp32->bf16 (sW = [4][262144]) and dmask->byte.
// ---------------------------------------------------------------------------
__global__ __launch_bounds__(256)
void conv_all(const float* __restrict__ strf,
              const float* __restrict__ Wq, const float* __restrict__ Wk,
              const float* __restrict__ Wv, const float* __restrict__ Wo,
              const int* __restrict__ dmask,
              unsigned short* __restrict__ sA, unsigned short* __restrict__ sW,
              unsigned char* __restrict__ mby)
{
    const long base = (long)(blockIdx.x * 256 + threadIdx.x) * 8;
    if (base >= 2097152) {
        const long rel = base - 2097152;
        int4 a = *reinterpret_cast<const int4*>(dmask + rel);
        int4 b = *reinterpret_cast<const int4*>(dmask + rel + 4);
        unsigned long long p = 0;
        p |= (a.x > 0) ? 0x01ULL : 0;  p |= (a.y > 0) ? 0x0100ULL : 0;
        p |= (a.z > 0) ? 0x010000ULL : 0;  p |= (a.w > 0) ? 0x01000000ULL : 0;
        p |= (b.x > 0) ? 0x0100000000ULL : 0;  p |= (b.y > 0) ? 0x010000000000ULL : 0;
        p |= (b.z > 0) ? 0x01000000000000ULL : 0;  p |= (b.w > 0) ? 0x0100000000000000ULL : 0;
        *reinterpret_cast<unsigned long long*>(mby + rel) = p;
        return;
    }
    const float* src;
    unsigned short* dst;
    if (base < 1048576) {
        src = strf + base; dst = sA + base;
    } else {
        const long rel = base - 1048576;
        const int seg = (int)(rel >> 18);
        const long off = rel & 262143;
        const float* Ws[4] = {Wq, Wk, Wv, Wo};
        src = Ws[seg] + off;
        dst = sW + (long)seg * 262144 + off;
    }
    float4 a = *reinterpret_cast<const float4*>(src);
    float4 b = *reinterpret_cast<const float4*>(src + 4);
    EU o;
    o.u[0] = f2bf(a.x); o.u[1] = f2bf(a.y); o.u[2] = f2bf(a.z); o.u[3] = f2bf(a.w);
    o.u[4] = f2bf(b.x); o.u[5] = f2bf(b.y); o.u[6] = f2bf(b.z); o.u[7] = f2bf(b.w);
    *reinterpret_cast<bf16x8*>(dst) = o.v;
}

// ---------------------------------------------------------------------------
// q/k/v projection via bf16 MFMA. grid (32 n-tiles, 8 d-tiles, 3).
// ---------------------------------------------------------------------------
__global__ __launch_bounds__(256)
void qkv_mfma(const unsigned short* __restrict__ sA,
              const unsigned short* __restrict__ sW,
              const float* __restrict__ bq, const float* __restrict__ bk,
              const float* __restrict__ bv,
              unsigned short* __restrict__ qh, unsigned short* __restrict__ kh,
              unsigned short* __restrict__ vT)
{
    const int z  = blockIdx.z;
    const int bx = blockIdx.x;
    const int by = blockIdx.y;
    const int tid = threadIdx.x;
    const int wv = tid >> 6;
    const int lane = tid & 63;
    const int row  = lane & 15;
    const int koct = (lane >> 4) * 8;
    const int n0 = bx * 64;

    const unsigned short* Ap = sA + (long)(n0 + wv * 16 + row) * 512;
    const unsigned short* Bp = sW + (long)z * 262144 + (long)(by * 64 + row) * 512;

    f32x4 acc[4] = {};
#pragma unroll
    for (int k0 = 0; k0 < 512; k0 += 32) {
        bf16x8 a = *reinterpret_cast<const bf16x8*>(Ap + k0 + koct);
#pragma unroll
        for (int t = 0; t < 4; t++) {
            bf16x8 b = *reinterpret_cast<const bf16x8*>(Bp + (long)(t * 16) * 512 + k0 + koct);
            acc[t] = __builtin_amdgcn_mfma_f32_16x16x32_bf16(a, b, acc[t], 0, 0, 0);
        }
    }

    if (z == 2) {
        const int rbase = n0 + wv * 16 + (lane >> 4) * 4;
#pragma unroll
        for (int t = 0; t < 4; t++) {
            const int d = by * 64 + t * 16 + (lane & 15);
            const float bb = bv[d];
            ushort4 o;
            o.x = f2bf(acc[t][0] + bb); o.y = f2bf(acc[t][1] + bb);
            o.z = f2bf(acc[t][2] + bb); o.w = f2bf(acc[t][3] + bb);
            *reinterpret_cast<ushort4*>(vT + (long)d * 2048 + rbase) = o;
        }
        return;
    }

    __shared__ float ls[64][68];
    const int lrb = wv * 16 + (lane >> 4) * 4;
    const int lcb = lane & 15;
#pragma unroll
    for (int t = 0; t < 4; t++)
#pragma unroll
        for (int r = 0; r < 4; r++)
            ls[lrb + r][t * 16 + lcb] = acc[t][r];
    __syncthreads();

    const float* bias = (z == 0) ? bq : bk;
    unsigned short* dst = (z == 0) ? qh : kh;
    const int r2 = tid >> 2;
    const int c2 = (tid & 3) * 16;
    float sv[16];
#pragma unroll
    for (int j = 0; j < 4; j++) {
        float4 s = *reinterpret_cast<const float4*>(&ls[r2][c2 + j * 4]);
        float4 bb = *reinterpret_cast<const float4*>(bias + by * 64 + c2 + j * 4);
        sv[j*4+0] = s.x + bb.x; sv[j*4+1] = s.y + bb.y;
        sv[j*4+2] = s.z + bb.z; sv[j*4+3] = s.w + bb.w;
    }
    EU o0, o1;
#pragma unroll
    for (int j = 0; j < 8; j++) { o0.u[j] = f2bf(sv[j]); o1.u[j] = f2bf(sv[8 + j]); }
    unsigned short* dp = dst + (long)(n0 + r2) * 512 + by * 64 + c2;
    *reinterpret_cast<bf16x8*>(dp)     = o0.v;
    *reinterpret_cast<bf16x8*>(dp + 8) = o1.v;
}

// ---------------------------------------------------------------------------
// ms_swp: one mean-shift sweep. grid (64 n-tiles of 32, 16 m-splits of 128);
// block 256 = 4 waves, wave owns 32 consecutive m. Swapped score MFMA ->
// exp*g -> cvt_pk -> shfl exchange -> K=32 reduce MFMA with A rows
// {1,xh,xl,yh,yl,zh,zl}. LDS only for the final cross-wave reduce.
// ---------------------------------------------------------------------------
__global__ __launch_bounds__(256)
void ms_swp(const unsigned short* __restrict__ qh,
            const unsigned short* __restrict__ kh,
            const unsigned char* __restrict__ mby,
            const float* __restrict__ xyz_src,
            const float* __restrict__ y_hat,
            const float* __restrict__ tptr,
            const float* __restrict__ bwp,
            float* __restrict__ Pzs)        // [8][2048][16][2] float4 = 8 MB
{
    const int n0 = blockIdx.x * 32;
    const int tid = threadIdx.x;
    const int wv = tid >> 6;
    const int lane = tid & 63;
    const int fr = lane & 15;
    const int g  = lane >> 4;
    const int koct = g * 8;
    const int mc = blockIdx.y * 128 + wv * 32;

    __shared__ float4 red[4][8][2][16][2];           // 32 KB per-h partials

    const float scale = 1.0f / (8.0f * tptr[0]);
    const float bw = bwp[0];
    const float c2k = 1.0f / (2.0f * bw * bw);

    // n-side scalars (two 16-n subtiles)
    float xn[2], yn[2], zn[2], sqn[2];
#pragma unroll
    for (int ns = 0; ns < 2; ns++) {
        const int n = n0 + ns * 16 + fr;
        const float x = xyz_src[n * 3 + 0];
        const float y = xyz_src[n * 3 + 1];
        const float z = xyz_src[n * 3 + 2];
        xn[ns] = x; yn[ns] = y; zn[ns] = z; sqn[ns] = x*x + y*y + z*z;
    }

    // masked g per (ns, m-offset 4g+r within tile t)
    float gm[2][8];
#pragma unroll
    for (int t = 0; t < 2; t++) {
        const int m0 = mc + t * 16 + g * 4;
        const float4 p0 = *reinterpret_cast<const float4*>(xyz_src + m0 * 3);
        const float4 p1 = *reinterpret_cast<const float4*>(xyz_src + m0 * 3 + 4);
        const float4 p2 = *reinterpret_cast<const float4*>(xyz_src + m0 * 3 + 8);
        const float mx[4] = {p0.x, p0.w, p1.z, p2.y};
        const float my[4] = {p0.y, p1.x, p1.w, p2.z};
        const float mz[4] = {p0.z, p1.y, p2.x, p2.w};
        const float4 yh4 = *reinterpret_cast<const float4*>(y_hat + m0);
        const float yhv[4] = {yh4.x, yh4.y, yh4.z, yh4.w};
        unsigned int mk[2];
        mk[0] = *reinterpret_cast<const unsigned int*>(mby + (long)(n0 + fr) * 2048 + m0);
        mk[1] = *reinterpret_cast<const unsigned int*>(mby + (long)(n0 + 16 + fr) * 2048 + m0);
#pragma unroll
        for (int r = 0; r < 4; r++) {
            const float sm = mx[r]*mx[r] + my[r]*my[r] + mz[r]*mz[r];
#pragma unroll
            for (int ns = 0; ns < 2; ns++) {
                const float d2 = sqn[ns] + sm
                               - 2.0f * (xn[ns]*mx[r] + yn[ns]*my[r] + zn[ns]*mz[r]);
                const float gv = __expf(-d2 * c2k) * yhv[r] + 1e-9f;
                gm[ns][t*4+r] = ((mk[ns] >> (8*r)) & 0xffu) ? gv : 0.0f;
            }
        }
    }

    // A-frag: rows {1, xh, xl, yh, yl, zh, zl, 0..}, k = m-offset 8g+jj
    EU ab;
    {
        const float* xp = xyz_src + (long)(mc + 8 * g) * 3;
        float qv[24];
#pragma unroll
        for (int i = 0; i < 6; i++)
            *reinterpret_cast<float4*>(&qv[i*4]) =
                *reinterpret_cast<const float4*>(xp + i*4);
#pragma unroll
        for (int jj = 0; jj < 8; jj++) {
            const float vx = qv[jj*3+0], vy = qv[jj*3+1], vz = qv[jj*3+2];
            const float cv = (fr < 3) ? vx : (fr < 5) ? vy : vz;
            const unsigned short hi = f2bf(cv);
            const unsigned short lo = f2bf(cv - bf2f(hi));
            unsigned short ov = (fr & 1) ? hi : lo;
            if (fr == 0) ov = 0x3F80;      // bf16 1.0
            if (fr >= 7) ov = 0;
            ab.u[jj] = ov;
        }
    }

#pragma unroll 2
    for (int h = 0; h < 8; h++) {
        bf16x8 a0[2], a1[2], b0[2], b1[2];
#pragma unroll
        for (int t = 0; t < 2; t++) {
            const unsigned short* Ap = kh + (long)(mc + t * 16 + fr) * 512 + h * 64;
            a0[t] = *reinterpret_cast<const bf16x8*>(Ap + koct);
            a1[t] = *reinterpret_cast<const bf16x8*>(Ap + 32 + koct);
        }
#pragma unroll
        for (int ns = 0; ns < 2; ns++) {
            const unsigned short* Bp = qh + (long)(n0 + ns * 16 + fr) * 512 + h * 64;
            b0[ns] = *reinterpret_cast<const bf16x8*>(Bp + koct);
            b1[ns] = *reinterpret_cast<const bf16x8*>(Bp + 32 + koct);
        }
        f32x4 c[2][2];
#pragma unroll
        for (int t = 0; t < 2; t++)
#pragma unroll
            for (int ns = 0; ns < 2; ns++) {
                f32x4 cc = {};
                cc = __builtin_amdgcn_mfma_f32_16x16x32_bf16(a0[t], b0[ns], cc, 0, 0, 0);
                cc = __builtin_amdgcn_mfma_f32_16x16x32_bf16(a1[t], b1[ns], cc, 0, 0, 0);
                c[t][ns] = cc;
            }
#pragma unroll
        for (int ns = 0; ns < 2; ns++) {
            float e[8];
#pragma unroll
            for (int t = 0; t < 2; t++)
#pragma unroll
                for (int r = 0; r < 4; r++)
                    e[t*4+r] = __expf(c[t][ns][r] * scale) * gm[ns][t*4+r];
            const unsigned int P0 = cvtpk(e[0], e[1]);
            const unsigned int P1 = cvtpk(e[2], e[3]);
            const unsigned int Q0 = cvtpk(e[4], e[5]);
            const unsigned int Q1 = cvtpk(e[6], e[7]);
            const bf16x8 fb = eg_exchange(P0, P1, Q0, Q1, g, fr);
            f32x4 cc = {};
            cc = __builtin_amdgcn_mfma_f32_16x16x32_bf16(ab.v, fb, cc, 0, 0, 0);
            if (g < 2)
                red[wv][h][ns][fr][g] = make_float4(cc[0], cc[1], cc[2], cc[3]);
        }
    }
    __syncthreads();

    // cross-wave reduce: 512 items, 2 per thread -> Pzs[h][n][slice][g]
#pragma unroll
    for (int it = 0; it < 2; it++) {
        const int idx = tid * 2 + it;
        const int gg = idx & 1;
        const int f2 = (idx >> 1) & 15;
        const int n2 = (idx >> 5) & 1;
        const int h2 = idx >> 6;
        float4 s0 = red[0][h2][n2][f2][gg];
        float4 s1 = red[1][h2][n2][f2][gg];
        float4 s2 = red[2][h2][n2][f2][gg];
        float4 s3 = red[3][h2][n2][f2][gg];
        float4 o = make_float4(s0.x+s1.x+s2.x+s3.x, s0.y+s1.y+s2.y+s3.y,
                               s0.z+s1.z+s2.z+s3.z, s0.w+s1.w+s2.w+s3.w);
        reinterpret_cast<float4*>(Pzs)[
            (((long)h2 * 2048 + n0 + n2 * 16 + f2) * 16 + blockIdx.y) * 2 + gg] = o;
    }
}

// ---------------------------------------------------------------------------
// ms_fin: per (n,h): sum 16 slices (512 B contiguous), invz, xyz mean.
// 16384 threads, grid 128x128.
// ---------------------------------------------------------------------------
__global__ __launch_bounds__(128)
void ms_fin(const float* __restrict__ Pzs,
            float* __restrict__ xyz_dst,
            float* __restrict__ invzb,
            int wlast)
{
    const int gid = blockIdx.x * 128 + threadIdx.x;   // 0..16383
    const int n = gid >> 3;
    const int h = gid & 7;
    const float4* P4 = reinterpret_cast<const float4*>(Pzs) + ((long)h * 2048 + n) * 32;
    float z = 0.f, sxh = 0.f, sxl = 0.f, syh = 0.f, syl = 0.f, szh = 0.f, szl = 0.f;
#pragma unroll
    for (int s = 0; s < 16; s++) {
        const float4 p0 = P4[s * 2];
        const float4 p1 = P4[s * 2 + 1];
        z += p0.x; sxh += p0.y; sxl += p0.z; syh += p0.w;
        syl += p1.x; szh += p1.y; szl += p1.z;
    }
    const float iz = 1.0f / z;
    if (wlast) invzb[h * 2048 + n] = iz;
    float cx = iz * (sxh + sxl);
    float cy = iz * (syh + syl);
    float cz = iz * (szh + szl);
#pragma unroll
    for (int d = 1; d < 8; d <<= 1) {
        cx += __shfl_xor(cx, d, 64);
        cy += __shfl_xor(cy, d, 64);
        cz += __shfl_xor(cz, d, 64);
    }
    if (h == 0) {
        xyz_dst[n * 3 + 0] = cx * 0.125f;
        xyz_dst[n * 3 + 1] = cy * 0.125f;
        xyz_dst[n * 3 + 2] = cz * 0.125f;
    }
}

// ---------------------------------------------------------------------------
// g_kern: gbf[n][m] = mask ? bf16(exp(-d2*c2k)*yh[m] + 1e-9) : 0.
// ---------------------------------------------------------------------------
__global__ __launch_bounds__(256)
void g_kern(const float* __restrict__ xyz4,
            const float* __restrict__ y_hat,
            const unsigned char* __restrict__ mby,
            const float* __restrict__ bwp,
            unsigned short* __restrict__ gbf)
{
    const int mc = blockIdx.x * 512;
    const int n0 = blockIdx.y * 8;
    const int tid = threadIdx.x;

    __shared__ float sxn[8], syn[8], szn[8], ssn[8];
    if (tid < 8) {
        const float x = xyz4[(n0 + tid) * 3 + 0];
        const float y = xyz4[(n0 + tid) * 3 + 1];
        const float z = xyz4[(n0 + tid) * 3 + 2];
        sxn[tid] = x; syn[tid] = y; szn[tid] = z; ssn[tid] = x*x + y*y + z*z;
    }
    __syncthreads();

    const float bw = bwp[0];
    const float c2k = 1.0f / (2.0f * bw * bw);
    const int m0 = mc + tid * 2;

    const float x0 = xyz4[m0 * 3 + 0], y0 = xyz4[m0 * 3 + 1], z0 = xyz4[m0 * 3 + 2];
    const float x1 = xyz4[m0 * 3 + 3], y1 = xyz4[m0 * 3 + 4], z1 = xyz4[m0 * 3 + 5];
    const float s0 = x0*x0 + y0*y0 + z0*z0;
    const float s1 = x1*x1 + y1*y1 + z1*z1;
    const float yh0 = y_hat[m0], yh1 = y_hat[m0 + 1];

#pragma unroll
    for (int r = 0; r < 8; r++) {
        const float xr = sxn[r], yr = syn[r], zr = szn[r], sr = ssn[r];
        const float d20 = sr + s0 - 2.0f * (xr*x0 + yr*y0 + zr*z0);
        const float d21 = sr + s1 - 2.0f * (xr*x1 + yr*y1 + zr*z1);
        const float g0 = __expf(-d20 * c2k) * yh0 + 1e-9f;
        const float g1 = __expf(-d21 * c2k) * yh1 + 1e-9f;
        const unsigned short mk2 = *reinterpret_cast<const unsigned short*>(
            mby + (long)(n0 + r) * 2048 + m0);
        ushort2 o;
        o.x = (mk2 & 0xff) ? f2bf(g0) : (unsigned short)0;
        o.y = (mk2 >> 8)   ? f2bf(g1) : (unsigned short)0;
        *reinterpret_cast<ushort2*>(gbf + (long)(n0 + r) * 2048 + m0) = o;
    }
}

// ---------------------------------------------------------------------------
// av_mfma: X = (E⊙g) @ v, E recomputed. grid (32 n-tiles of 64, 4 m-splits,
// 8 heads); wave = one 16-n subtile. vT AND kh staged per 128-m group into
// XOR-swizzled LDS (same verified pattern). Score -> exp*g -> cvt_pk ->
// shfl exchange -> K=32 PV MFMA. No conflicted DS ops.
// ---------------------------------------------------------------------------
__global__ __launch_bounds__(256)
void av_mfma(const unsigned short* __restrict__ qh,
             const unsigned short* __restrict__ kh,
             const unsigned short* __restrict__ gbf,  // [2048][2048] masked
             const unsigned short* __restrict__ vT,   // [512][2048]
             const float* __restrict__ tptr,
             float* __restrict__ P)                   // [4][2048][512]
{
    const int h  = blockIdx.z;
    const int s  = blockIdx.y;
    const int bx = blockIdx.x;
    const int tid = threadIdx.x;
    const int wv = tid >> 6;
    const int lane = tid & 63;
    const int fr = lane & 15;
    const int g  = lane >> 4;
    const int koct = g * 8;
    const int n0 = bx * 64;

    __shared__ unsigned short vts[8192];      // [64 d][128 m] swizzled, 16 KB
    __shared__ unsigned short khs[8192];      // [128 m][64 dh] swizzled, 16 KB

    const float scale = 1.0f / (8.0f * tptr[0]);

    const unsigned short* Bp = qh + (long)(n0 + wv * 16 + fr) * 512 + h * 64;
    const bf16x8 b0 = *reinterpret_cast<const bf16x8*>(Bp + koct);
    const bf16x8 b1 = *reinterpret_cast<const bf16x8*>(Bp + 32 + koct);

    const unsigned short* grow = gbf + (long)(n0 + wv * 16 + fr) * 2048;
    const int sx = (fr & 7) << 4;

    f32x4 acc[4] = {};
    for (int grp = 0; grp < 4; grp++) {
        const int m0g = s * 512 + grp * 128;
        __syncthreads();
        // stage vT[h][0..63][m0g..+128) -> swizzled vts (rows 256 B)
#pragma unroll
        for (int i = 0; i < 4; i++) {
            const int bo = tid * 16 + i * 4096;
            const int row = bo >> 8;
            const int swz = bo ^ ((row & 7) << 4);
            const bf16x8 v = *reinterpret_cast<const bf16x8*>(
                vT + ((long)h * 64 + row) * 2048 + m0g + ((bo & 255) >> 1));
            *reinterpret_cast<bf16x8*>(reinterpret_cast<char*>(vts) + swz) = v;
        }
        // stage kh[m0g..+128)[h*64..+64) -> swizzled khs (rows 128 B)
#pragma unroll
        for (int i = 0; i < 4; i++) {
            const int bo = tid * 16 + i * 4096;
            const int row = bo >> 7;
            const int swz = bo ^ ((row & 7) << 4);
            const bf16x8 v = *reinterpret_cast<const bf16x8*>(
                kh + (long)(m0g + row) * 512 + h * 64 + ((bo & 127) >> 1));
            *reinterpret_cast<bf16x8*>(reinterpret_cast<char*>(khs) + swz) = v;
        }
        __syncthreads();
#pragma unroll
        for (int mblk = 0; mblk < 4; mblk++) {
            const int m0 = m0g + mblk * 32;
            // scores from LDS kh (swizzled, conflict-free)
            f32x4 c[2];
#pragma unroll
            for (int t = 0; t < 2; t++) {
                const int lr = mblk * 32 + t * 16 + fr;
                const int cbase = (lr << 7) + (g << 4);
                const bf16x8 alo = *reinterpret_cast<const bf16x8*>(
                    reinterpret_cast<const char*>(khs) + (cbase ^ sx));
                const bf16x8 ahi = *reinterpret_cast<const bf16x8*>(
                    reinterpret_cast<const char*>(khs) + ((cbase + 64) ^ sx));
                f32x4 cc = {};
                cc = __builtin_amdgcn_mfma_f32_16x16x32_bf16(alo, b0, cc, 0, 0, 0);
                cc = __builtin_amdgcn_mfma_f32_16x16x32_bf16(ahi, b1, cc, 0, 0, 0);
                c[t] = cc;
            }
            const ushort4 g0 = *reinterpret_cast<const ushort4*>(grow + m0 + 4 * g);
            const ushort4 g1 = *reinterpret_cast<const ushort4*>(grow + m0 + 16 + 4 * g);
            const unsigned int P0 = cvtpk(__expf(c[0][0]*scale)*bf2f(g0.x),
                                          __expf(c[0][1]*scale)*bf2f(g0.y));
            const unsigned int P1 = cvtpk(__expf(c[0][2]*scale)*bf2f(g0.z),
                                          __expf(c[0][3]*scale)*bf2f(g0.w));
            const unsigned int Q0 = cvtpk(__expf(c[1][0]*scale)*bf2f(g1.x),
                                          __expf(c[1][1]*scale)*bf2f(g1.y));
            const unsigned int Q1 = cvtpk(__expf(c[1][2]*scale)*bf2f(g1.z),
                                          __expf(c[1][3]*scale)*bf2f(g1.w));
            const bf16x8 fb = eg_exchange(P0, P1, Q0, Q1, g, fr);
#pragma unroll
            for (int dt = 0; dt < 4; dt++) {
                const int bofs = (((dt * 16 + fr) << 8) + mblk * 64 + g * 16) ^ sx;
                const bf16x8 avt = *reinterpret_cast<const bf16x8*>(
                    reinterpret_cast<const char*>(vts) + bofs);
                acc[dt] = __builtin_amdgcn_mfma_f32_16x16x32_bf16(avt, fb, acc[dt], 0, 0, 0);
            }
        }
    }

    float* Pp = P + (long)s * 1048576;
#pragma unroll
    for (int dt = 0; dt < 4; dt++)
        *reinterpret_cast<float4*>(
            &Pp[(long)(n0 + wv * 16 + fr) * 512 + h * 64 + dt * 16 + 4 * g]) =
            *reinterpret_cast<const float4*>(&acc[dt]);
}

// ---------------------------------------------------------------------------
// xc[n][d] bf16 = invz_h[n] * sum of 4 fp32 partials. 8 elems/thread.
// ---------------------------------------------------------------------------
__global__ __launch_bounds__(256)
void av_red(const float* __restrict__ P, const float* __restrict__ invzb,
            unsigned short* __restrict__ xc)
{
    const long idx = (long)(blockIdx.x * 256 + threadIdx.x) * 8;
    const int n = (int)(idx >> 9);
    const int d0 = (int)(idx & 511);
    const float iz = invzb[(d0 >> 6) * 2048 + n];
    float s[8] = {};
#pragma unroll
    for (int p = 0; p < 4; p++) {
        const float* pp = P + (long)p * 1048576 + idx;
        float4 a = *reinterpret_cast<const float4*>(pp);
        float4 b = *reinterpret_cast<const float4*>(pp + 4);
        s[0] += a.x; s[1] += a.y; s[2] += a.z; s[3] += a.w;
        s[4] += b.x; s[5] += b.y; s[6] += b.z; s[7] += b.w;
    }
    EU o;
#pragma unroll
    for (int j = 0; j < 8; j++) o.u[j] = f2bf(s[j] * iz);
    *reinterpret_cast<bf16x8*>(xc + idx) = o.v;
}

// ---------------------------------------------------------------------------
// out = xc @ Wo.T + bo via bf16 MFMA, fp32 out. grid (32 n-tiles, 8 d-tiles).
// ---------------------------------------------------------------------------
__global__ __launch_bounds__(256)
void out_mfma(const unsigned short* __restrict__ xc,
              const unsigned short* __restrict__ sW,   // seg 3 = Wo
              const float* __restrict__ bo,
              float* __restrict__ out)
{
    const int bx = blockIdx.x;
    const int by = blockIdx.y;
    const int wv = threadIdx.x >> 6;
    const int lane = threadIdx.x & 63;
    const int row  = lane & 15;
    const int koct = (lane >> 4) * 8;
    const int n0 = bx * 64;

    const unsigned short* Ap = xc + (long)(n0 + wv * 16 + row) * 512;
    const unsigned short* Bp = sW + 3L * 262144 + (long)(by * 64 + row) * 512;

    f32x4 acc[4] = {};
#pragma unroll
    for (int k0 = 0; k0 < 512; k0 += 32) {
        bf16x8 a = *reinterpret_cast<const bf16x8*>(Ap + k0 + koct);
#pragma unroll
        for (int t = 0; t < 4; t++) {
            bf16x8 b = *reinterpret_cast<const bf16x8*>(Bp + (long)(t * 16) * 512 + k0 + koct);
            acc[t] = __builtin_amdgcn_mfma_f32_16x16x32_bf16(a, b, acc[t], 0, 0, 0);
        }
    }

    const int rbase = n0 + wv * 16 + (lane >> 4) * 4;
    const int dcol = lane & 15;
#pragma unroll
    for (int t = 0; t < 4; t++) {
        const int col = by * 64 + t * 16 + dcol;
        const float bb = bo[col];
#pragma unroll
        for (int r = 0; r < 4; r++)
            out[(long)(rbase + r) * 512 + col] = acc[t][r] + bb;
    }
}

// ---------------------------------------------------------------------------
extern "C" void kernel_launch(void* const* d_in, const int* in_sizes, int n_in,
                              void* d_out, int out_size, void* d_ws, size_t ws_size,
                              hipStream_t stream)
{
    (void)in_sizes; (void)n_in; (void)out_size; (void)ws_size;

    const float* xyz   = (const float*)d_in[0];
    const float* strf  = (const float*)d_in[1];
    // d_in[2] esm_feat: dead code (DCE'd in reference)
    const float* yhat  = (const float*)d_in[3];
    const int*   dmask = (const int*)d_in[4];
    const float* tptr  = (const float*)d_in[5];
    const float* bwptr = (const float*)d_in[6];
    // d_in[7] max_iter = 5 (fixed)
    const float* Wq = (const float*)d_in[8];
    const float* bq = (const float*)d_in[9];
    const float* Wk = (const float*)d_in[10];
    const float* bk = (const float*)d_in[11];
    const float* Wv = (const float*)d_in[12];
    const float* bv = (const float*)d_in[13];
    const float* Wo = (const float*)d_in[14];
    const float* bo = (const float*)d_in[15];
    float* outp = (float*)d_out;

    char* wsb = (char*)d_ws;
    float* Ppart         = (float*)(wsb);                        // 16 MB
    unsigned short* xc   = (unsigned short*)(wsb + (16L << 20)); // 2 MB
    unsigned short* sA   = (unsigned short*)(wsb + (18L << 20)); // 2 MB
    unsigned short* sW   = (unsigned short*)(wsb + (20L << 20)); // 2 MB
    unsigned short* qh   = (unsigned short*)(wsb + (22L << 20)); // 2 MB
    unsigned short* kh   = (unsigned short*)(wsb + (24L << 20)); // 2 MB
    unsigned short* vT   = (unsigned short*)(wsb + (26L << 20)); // 2 MB
    float* xyzA          = (float*)(wsb + (28L << 20));
    float* xyzB          = xyzA + 8192;
    unsigned char* mby   = (unsigned char*)(wsb + (30L << 20));  // 4 MB
    float* Pzs           = (float*)(wsb + (34L << 20));          // [8][2048][16][2]f4, 8 MB
    unsigned short* gbf  = (unsigned short*)(wsb + (50L << 20)); // 8 MB
    float* invzb         = (float*)(wsb + (58L << 20));          // 64 KB

    dim3 blk(256, 1, 1);

    conv_all<<<dim3(3072), blk, 0, stream>>>(strf, Wq, Wk, Wv, Wo, dmask, sA, sW, mby);
    qkv_mfma<<<dim3(32, 8, 3), blk, 0, stream>>>(sA, sW, bq, bk, bv, qh, kh, vT);

    // 5 mean-shift iterations: MFMA-reduced fused sweep + tiny slice reduce
    const float* src = xyz;
    float* dsts[5] = {xyzA, xyzB, xyzA, xyzB, outp};
    for (int it = 0; it < 5; it++) {
        ms_swp<<<dim3(64, 16), blk, 0, stream>>>(qh, kh, mby, src, yhat, tptr, bwptr, Pzs);
        ms_fin<<<dim3(128), dim3(128), 0, stream>>>(Pzs, dsts[it], invzb, it == 4 ? 1 : 0);
        src = dsts[it];
    }

    g_kern<<<dim3(4, 256), blk, 0, stream>>>(xyzB, yhat, mby, bwptr, gbf);
    av_mfma<<<dim3(32, 4, 8), blk, 0, stream>>>(qh, kh, gbf, vT, tptr, Ppart);
    av_red<<<dim3(512), blk, 0, stream>>>(Ppart, invzb, xc);
    out_mfma<<<dim3(32, 8), blk, 0, stream>>>(xc, sW, bo, outp + 6144);
}

// Round 8
// 332.875 us; speedup vs baseline: 1.5389x; 1.2095x over previous
//
#include <hip/hip_runtime.h>

// Problem constants (fixed by setup_inputs): N=2048, D=512, H=8, dh=64, max_iter=5.
// Identity: exp(s/t + log(kern*yw+eps)) = exp(s/(8t)) * (kern*yw+eps).
// R8 = R7 with ms_swp's memory path restructured (same medicine that fixed
// av_mfma in R7): per h, the block cooperatively stages kh (32 KB) and qh
// (4 KB) into XOR-swizzled LDS (the verified av pattern), replacing per-lane
// scattered 16 B L2 reads + 4x-redundant qh wave reads. Grid (64,8): wave
// owns 64 m as 2 chunks of 32, chunk results summed through the reduce-MFMA
// accumulator. Exchange (shfl) + reduce-MFMA path byte-identical to R7.
// Pzs slices 16 -> 8. av/g_kern/conv/qkv/av_red/out byte-identical to R7.

typedef __attribute__((ext_vector_type(8))) short bf16x8;
typedef __attribute__((ext_vector_type(4))) float f32x4;

__device__ __forceinline__ unsigned short f2bf(float f) {
    unsigned int u = __float_as_uint(f);
    u += 0x7fff + ((u >> 16) & 1);   // RNE (inputs finite)
    return (unsigned short)(u >> 16);
}
__device__ __forceinline__ float bf2f(unsigned short u) {
    return __uint_as_float((unsigned int)u << 16);
}
__device__ __forceinline__ unsigned int cvtpk(float lo, float hi) {
    unsigned int r;
    asm volatile("v_cvt_pk_bf16_f32 %0, %1, %2" : "=v"(r) : "v"(lo), "v"(hi));
    return r;
}

union EU { bf16x8 v; unsigned short u[8]; };

// shfl-based EG exchange (R7-verified): dest lane (g,fr) gets the K=32 B-frag
// dwords from lanes srcA=(g&1)*32+fr (dwords 0-1) and srcB=srcA+16 (2-3),
// pair selected by g>>1.
__device__ __forceinline__ bf16x8 eg_exchange(unsigned int P0, unsigned int P1,
                                              unsigned int Q0, unsigned int Q1,
                                              int g, int fr) {
    const int srcA = (g & 1) * 32 + fr;
    const int srcB = srcA + 16;
    const bool selQ = (g >> 1) != 0;
    const unsigned int a0 = (unsigned int)__shfl((int)P0, srcA, 64);
    const unsigned int a1 = (unsigned int)__shfl((int)P1, srcA, 64);
    const unsigned int a2 = (unsigned int)__shfl((int)Q0, srcA, 64);
    const unsigned int a3 = (unsigned int)__shfl((int)Q1, srcA, 64);
    const unsigned int b0 = (unsigned int)__shfl((int)P0, srcB, 64);
    const unsigned int b1 = (unsigned int)__shfl((int)P1, srcB, 64);
    const unsigned int b2 = (unsigned int)__shfl((int)Q0, srcB, 64);
    const unsigned int b3 = (unsigned int)__shfl((int)Q1, srcB, 64);
    union { int4 i; bf16x8 v; } fb;
    fb.i = make_int4((int)(selQ ? a2 : a0), (int)(selQ ? a3 : a1),
                     (int)(selQ ? b2 : b0), (int)(selQ ? b3 : b1));
    return fb.v;
}

// ---------------------------------------------------------------------------
// Convert strf + Wq/Wk/Wv/Wo fp32->bf16 (sW = [4][262144]) and dmask->byte.
// ---------------------------------------------------------------------------
__global__ __launch_bounds__(256)
void conv_all(const float* __restrict__ strf,
              const float* __restrict__ Wq, const float* __restrict__ Wk,
              const float* __restrict__ Wv, const float* __restrict__ Wo,
              const int* __restrict__ dmask,
              unsigned short* __restrict__ sA, unsigned short* __restrict__ sW,
              unsigned char* __restrict__ mby)
{
    const long base = (long)(blockIdx.x * 256 + threadIdx.x) * 8;
    if (base >= 2097152) {
        const long rel = base - 2097152;
        int4 a = *reinterpret_cast<const int4*>(dmask + rel);
        int4 b = *reinterpret_cast<const int4*>(dmask + rel + 4);
        unsigned long long p = 0;
        p |= (a.x > 0) ? 0x01ULL : 0;  p |= (a.y > 0) ? 0x0100ULL : 0;
        p |= (a.z > 0) ? 0x010000ULL : 0;  p |= (a.w > 0) ? 0x01000000ULL : 0;
        p |= (b.x > 0) ? 0x0100000000ULL : 0;  p |= (b.y > 0) ? 0x010000000000ULL : 0;
        p |= (b.z > 0) ? 0x01000000000000ULL : 0;  p |= (b.w > 0) ? 0x0100000000000000ULL : 0;
        *reinterpret_cast<unsigned long long*>(mby + rel) = p;
        return;
    }
    const float* src;
    unsigned short* dst;
    if (base < 1048576) {
        src = strf + base; dst = sA + base;
    } else {
        const long rel = base - 1048576;
        const int seg = (int)(rel >> 18);
        const long off = rel & 262143;
        const float* Ws[4] = {Wq, Wk, Wv, Wo};
        src = Ws[seg] + off;
        dst = sW + (long)seg * 262144 + off;
    }
    float4 a = *reinterpret_cast<const float4*>(src);
    float4 b = *reinterpret_cast<const float4*>(src + 4);
    EU o;
    o.u[0] = f2bf(a.x); o.u[1] = f2bf(a.y); o.u[2] = f2bf(a.z); o.u[3] = f2bf(a.w);
    o.u[4] = f2bf(b.x); o.u[5] = f2bf(b.y); o.u[6] = f2bf(b.z); o.u[7] = f2bf(b.w);
    *reinterpret_cast<bf16x8*>(dst) = o.v;
}

// ---------------------------------------------------------------------------
// q/k/v projection via bf16 MFMA. grid (32 n-tiles, 8 d-tiles, 3).
// ---------------------------------------------------------------------------
__global__ __launch_bounds__(256)
void qkv_mfma(const unsigned short* __restrict__ sA,
              const unsigned short* __restrict__ sW,
              const float* __restrict__ bq, const float* __restrict__ bk,
              const float* __restrict__ bv,
              unsigned short* __restrict__ qh, unsigned short* __restrict__ kh,
              unsigned short* __restrict__ vT)
{
    const int z  = blockIdx.z;
    const int bx = blockIdx.x;
    const int by = blockIdx.y;
    const int tid = threadIdx.x;
    const int wv = tid >> 6;
    const int lane = tid & 63;
    const int row  = lane & 15;
    const int koct = (lane >> 4) * 8;
    const int n0 = bx * 64;

    const unsigned short* Ap = sA + (long)(n0 + wv * 16 + row) * 512;
    const unsigned short* Bp = sW + (long)z * 262144 + (long)(by * 64 + row) * 512;

    f32x4 acc[4] = {};
#pragma unroll
    for (int k0 = 0; k0 < 512; k0 += 32) {
        bf16x8 a = *reinterpret_cast<const bf16x8*>(Ap + k0 + koct);
#pragma unroll
        for (int t = 0; t < 4; t++) {
            bf16x8 b = *reinterpret_cast<const bf16x8*>(Bp + (long)(t * 16) * 512 + k0 + koct);
            acc[t] = __builtin_amdgcn_mfma_f32_16x16x32_bf16(a, b, acc[t], 0, 0, 0);
        }
    }

    if (z == 2) {
        const int rbase = n0 + wv * 16 + (lane >> 4) * 4;
#pragma unroll
        for (int t = 0; t < 4; t++) {
            const int d = by * 64 + t * 16 + (lane & 15);
            const float bb = bv[d];
            ushort4 o;
            o.x = f2bf(acc[t][0] + bb); o.y = f2bf(acc[t][1] + bb);
            o.z = f2bf(acc[t][2] + bb); o.w = f2bf(acc[t][3] + bb);
            *reinterpret_cast<ushort4*>(vT + (long)d * 2048 + rbase) = o;
        }
        return;
    }

    __shared__ float ls[64][68];
    const int lrb = wv * 16 + (lane >> 4) * 4;
    const int lcb = lane & 15;
#pragma unroll
    for (int t = 0; t < 4; t++)
#pragma unroll
        for (int r = 0; r < 4; r++)
            ls[lrb + r][t * 16 + lcb] = acc[t][r];
    __syncthreads();

    const float* bias = (z == 0) ? bq : bk;
    unsigned short* dst = (z == 0) ? qh : kh;
    const int r2 = tid >> 2;
    const int c2 = (tid & 3) * 16;
    float sv[16];
#pragma unroll
    for (int j = 0; j < 4; j++) {
        float4 s = *reinterpret_cast<const float4*>(&ls[r2][c2 + j * 4]);
        float4 bb = *reinterpret_cast<const float4*>(bias + by * 64 + c2 + j * 4);
        sv[j*4+0] = s.x + bb.x; sv[j*4+1] = s.y + bb.y;
        sv[j*4+2] = s.z + bb.z; sv[j*4+3] = s.w + bb.w;
    }
    EU o0, o1;
#pragma unroll
    for (int j = 0; j < 8; j++) { o0.u[j] = f2bf(sv[j]); o1.u[j] = f2bf(sv[8 + j]); }
    unsigned short* dp = dst + (long)(n0 + r2) * 512 + by * 64 + c2;
    *reinterpret_cast<bf16x8*>(dp)     = o0.v;
    *reinterpret_cast<bf16x8*>(dp + 8) = o1.v;
}

// ---------------------------------------------------------------------------
// ms_swp: one mean-shift sweep. grid (64 n-tiles of 32, 8 m-splits of 256);
// block 256 = 4 waves, wave owns 64 consecutive m (2 chunks of 32, summed
// through the reduce-MFMA accumulator). Per h: block stages kh (256 rows x
// 64 cols, 32 KB) + qh (32 x 64, 4 KB) into XOR-swizzled LDS; all fragment
// reads from LDS (conflict-free, no scattered L2 traffic, no qh redundancy).
// Score -> exp*g -> cvt_pk -> shfl exchange -> K=32 reduce MFMA with A rows
// {1,xh,xl,yh,yl,zh,zl} (R7-verified path).
// ---------------------------------------------------------------------------
__global__ __launch_bounds__(256)
void ms_swp(const unsigned short* __restrict__ qh,
            const unsigned short* __restrict__ kh,
            const unsigned char* __restrict__ mby,
            const float* __restrict__ xyz_src,
            const float* __restrict__ y_hat,
            const float* __restrict__ tptr,
            const float* __restrict__ bwp,
            float* __restrict__ Pzs)        // [8][2048][8][2] float4 = 4 MB
{
    const int n0 = blockIdx.x * 32;
    const int mb = blockIdx.y * 256;
    const int tid = threadIdx.x;
    const int wv = tid >> 6;
    const int lane = tid & 63;
    const int fr = lane & 15;
    const int g  = lane >> 4;

    __shared__ unsigned short khs[16384];    // [256 m][64 dh] swizzled, 32 KB
    __shared__ unsigned short qhs[2048];     // [32 n][64 dh] swizzled, 4 KB
    __shared__ float4 red[4][8][2][16][2];   // 32 KB per-h partials

    const float scale = 1.0f / (8.0f * tptr[0]);
    const float bw = bwp[0];
    const float c2k = 1.0f / (2.0f * bw * bw);

    // n-side scalars (two 16-n subtiles)
    float xn[2], yn[2], zn[2], sqn[2];
#pragma unroll
    for (int ns = 0; ns < 2; ns++) {
        const int n = n0 + ns * 16 + fr;
        const float x = xyz_src[n * 3 + 0];
        const float y = xyz_src[n * 3 + 1];
        const float z = xyz_src[n * 3 + 2];
        xn[ns] = x; yn[ns] = y; zn[ns] = z; sqn[ns] = x*x + y*y + z*z;
    }

    // per chunk c (32 m), tile t (16 m): masked g and coef A-frag
    float gm[2][2][8];     // [c][ns][t*4+r]
    EU ab[2];              // [c] rows {1,xh,xl,yh,yl,zh,zl,0}, k = 8g+jj
#pragma unroll
    for (int c = 0; c < 2; c++) {
        const int mc = mb + wv * 64 + c * 32;
#pragma unroll
        for (int t = 0; t < 2; t++) {
            const int m0 = mc + t * 16 + g * 4;
            const float4 p0 = *reinterpret_cast<const float4*>(xyz_src + m0 * 3);
            const float4 p1 = *reinterpret_cast<const float4*>(xyz_src + m0 * 3 + 4);
            const float4 p2 = *reinterpret_cast<const float4*>(xyz_src + m0 * 3 + 8);
            const float mx[4] = {p0.x, p0.w, p1.z, p2.y};
            const float my[4] = {p0.y, p1.x, p1.w, p2.z};
            const float mz[4] = {p0.z, p1.y, p2.x, p2.w};
            const float4 yh4 = *reinterpret_cast<const float4*>(y_hat + m0);
            const float yhv[4] = {yh4.x, yh4.y, yh4.z, yh4.w};
            unsigned int mk[2];
            mk[0] = *reinterpret_cast<const unsigned int*>(mby + (long)(n0 + fr) * 2048 + m0);
            mk[1] = *reinterpret_cast<const unsigned int*>(mby + (long)(n0 + 16 + fr) * 2048 + m0);
#pragma unroll
            for (int r = 0; r < 4; r++) {
                const float sm = mx[r]*mx[r] + my[r]*my[r] + mz[r]*mz[r];
#pragma unroll
                for (int ns = 0; ns < 2; ns++) {
                    const float d2 = sqn[ns] + sm
                                   - 2.0f * (xn[ns]*mx[r] + yn[ns]*my[r] + zn[ns]*mz[r]);
                    const float gv = __expf(-d2 * c2k) * yhv[r] + 1e-9f;
                    gm[c][ns][t*4+r] = ((mk[ns] >> (8*r)) & 0xffu) ? gv : 0.0f;
                }
            }
        }
        // coef A-frag for chunk c (k = m-offset 8g+jj within the 32-m chunk)
        const float* xp = xyz_src + (long)(mc + 8 * g) * 3;
        float qv[24];
#pragma unroll
        for (int i = 0; i < 6; i++)
            *reinterpret_cast<float4*>(&qv[i*4]) =
                *reinterpret_cast<const float4*>(xp + i*4);
#pragma unroll
        for (int jj = 0; jj < 8; jj++) {
            const float vx = qv[jj*3+0], vy = qv[jj*3+1], vz = qv[jj*3+2];
            const float cv = (fr < 3) ? vx : (fr < 5) ? vy : vz;
            const unsigned short hi = f2bf(cv);
            const unsigned short lo = f2bf(cv - bf2f(hi));
            unsigned short ov = (fr & 1) ? hi : lo;
            if (fr == 0) ov = 0x3F80;      // bf16 1.0
            if (fr >= 7) ov = 0;
            ab[c].u[jj] = ov;
        }
    }

    for (int h = 0; h < 8; h++) {
        __syncthreads();   // previous h's LDS reads complete before overwrite
        // stage kh[mb..mb+256)[h*64..+64) -> swizzled khs (rows 128 B)
#pragma unroll
        for (int i = 0; i < 8; i++) {
            const int bo = tid * 16 + i * 4096;
            const int row = bo >> 7;
            const int swz = bo ^ ((row & 7) << 4);
            const bf16x8 v = *reinterpret_cast<const bf16x8*>(
                kh + (long)(mb + row) * 512 + h * 64 + ((bo & 127) >> 1));
            *reinterpret_cast<bf16x8*>(reinterpret_cast<char*>(khs) + swz) = v;
        }
        // stage qh[n0..n0+32)[h*64..+64) -> swizzled qhs (rows 128 B)
        {
            const int bo = tid * 16;
            const int row = bo >> 7;
            const int swz = bo ^ ((row & 7) << 4);
            const bf16x8 v = *reinterpret_cast<const bf16x8*>(
                qh + (long)(n0 + row) * 512 + h * 64 + ((bo & 127) >> 1));
            *reinterpret_cast<bf16x8*>(reinterpret_cast<char*>(qhs) + swz) = v;
        }
        __syncthreads();

        // qh B-frags for the two n-subtiles (from LDS)
        bf16x8 b0[2], b1[2];
#pragma unroll
        for (int ns = 0; ns < 2; ns++) {
            const int row = ns * 16 + fr;
            const int cb = (row << 7) + (g << 4);
            const int sw = (row & 7) << 4;
            b0[ns] = *reinterpret_cast<const bf16x8*>(
                reinterpret_cast<const char*>(qhs) + (cb ^ sw));
            b1[ns] = *reinterpret_cast<const bf16x8*>(
                reinterpret_cast<const char*>(qhs) + ((cb + 64) ^ sw));
        }

        f32x4 out_ns[2] = {};
#pragma unroll
        for (int c = 0; c < 2; c++) {
            // kh A-frags for chunk c (from LDS)
            f32x4 sc[2][2];
#pragma unroll
            for (int t = 0; t < 2; t++) {
                const int row = wv * 64 + c * 32 + t * 16 + fr;
                const int cb = (row << 7) + (g << 4);
                const int sw = (row & 7) << 4;
                const bf16x8 a0 = *reinterpret_cast<const bf16x8*>(
                    reinterpret_cast<const char*>(khs) + (cb ^ sw));
                const bf16x8 a1 = *reinterpret_cast<const bf16x8*>(
                    reinterpret_cast<const char*>(khs) + ((cb + 64) ^ sw));
#pragma unroll
                for (int ns = 0; ns < 2; ns++) {
                    f32x4 cc = {};
                    cc = __builtin_amdgcn_mfma_f32_16x16x32_bf16(a0, b0[ns], cc, 0, 0, 0);
                    cc = __builtin_amdgcn_mfma_f32_16x16x32_bf16(a1, b1[ns], cc, 0, 0, 0);
                    sc[t][ns] = cc;
                }
            }
#pragma unroll
            for (int ns = 0; ns < 2; ns++) {
                float e[8];
#pragma unroll
                for (int t = 0; t < 2; t++)
#pragma unroll
                    for (int r = 0; r < 4; r++)
                        e[t*4+r] = __expf(sc[t][ns][r] * scale) * gm[c][ns][t*4+r];
                const unsigned int P0 = cvtpk(e[0], e[1]);
                const unsigned int P1 = cvtpk(e[2], e[3]);
                const unsigned int Q0 = cvtpk(e[4], e[5]);
                const unsigned int Q1 = cvtpk(e[6], e[7]);
                const bf16x8 fb = eg_exchange(P0, P1, Q0, Q1, g, fr);
                out_ns[ns] = __builtin_amdgcn_mfma_f32_16x16x32_bf16(
                    ab[c].v, fb, out_ns[ns], 0, 0, 0);
            }
        }
        if (g < 2) {
#pragma unroll
            for (int ns = 0; ns < 2; ns++)
                red[wv][h][ns][fr][g] = make_float4(out_ns[ns][0], out_ns[ns][1],
                                                    out_ns[ns][2], out_ns[ns][3]);
        }
    }
    __syncthreads();

    // cross-wave reduce: 512 items, 2 per thread -> Pzs[h][n][slice][g]
#pragma unroll
    for (int it = 0; it < 2; it++) {
        const int idx = tid * 2 + it;
        const int gg = idx & 1;
        const int f2 = (idx >> 1) & 15;
        const int n2 = (idx >> 5) & 1;
        const int h2 = idx >> 6;
        float4 s0 = red[0][h2][n2][f2][gg];
        float4 s1 = red[1][h2][n2][f2][gg];
        float4 s2 = red[2][h2][n2][f2][gg];
        float4 s3 = red[3][h2][n2][f2][gg];
        float4 o = make_float4(s0.x+s1.x+s2.x+s3.x, s0.y+s1.y+s2.y+s3.y,
                               s0.z+s1.z+s2.z+s3.z, s0.w+s1.w+s2.w+s3.w);
        reinterpret_cast<float4*>(Pzs)[
            (((long)h2 * 2048 + n0 + n2 * 16 + f2) * 8 + blockIdx.y) * 2 + gg] = o;
    }
}

// ---------------------------------------------------------------------------
// ms_fin: per (n,h): sum 8 slices (256 B contiguous), invz, xyz mean.
// 16384 threads, grid 128x128.
// ---------------------------------------------------------------------------
__global__ __launch_bounds__(128)
void ms_fin(const float* __restrict__ Pzs,
            float* __restrict__ xyz_dst,
            float* __restrict__ invzb,
            int wlast)
{
    const int gid = blockIdx.x * 128 + threadIdx.x;   // 0..16383
    const int n = gid >> 3;
    const int h = gid & 7;
    const float4* P4 = reinterpret_cast<const float4*>(Pzs) + ((long)h * 2048 + n) * 16;
    float z = 0.f, sxh = 0.f, sxl = 0.f, syh = 0.f, syl = 0.f, szh = 0.f, szl = 0.f;
#pragma unroll
    for (int s = 0; s < 8; s++) {
        const float4 p0 = P4[s * 2];
        const float4 p1 = P4[s * 2 + 1];
        z += p0.x; sxh += p0.y; sxl += p0.z; syh += p0.w;
        syl += p1.x; szh += p1.y; szl += p1.z;
    }
    const float iz = 1.0f / z;
    if (wlast) invzb[h * 2048 + n] = iz;
    float cx = iz * (sxh + sxl);
    float cy = iz * (syh + syl);
    float cz = iz * (szh + szl);
#pragma unroll
    for (int d = 1; d < 8; d <<= 1) {
        cx += __shfl_xor(cx, d, 64);
        cy += __shfl_xor(cy, d, 64);
        cz += __shfl_xor(cz, d, 64);
    }
    if (h == 0) {
        xyz_dst[n * 3 + 0] = cx * 0.125f;
        xyz_dst[n * 3 + 1] = cy * 0.125f;
        xyz_dst[n * 3 + 2] = cz * 0.125f;
    }
}

// ---------------------------------------------------------------------------
// g_kern: gbf[n][m] = mask ? bf16(exp(-d2*c2k)*yh[m] + 1e-9) : 0.
// ---------------------------------------------------------------------------
__global__ __launch_bounds__(256)
void g_kern(const float* __restrict__ xyz4,
            const float* __restrict__ y_hat,
            const unsigned char* __restrict__ mby,
            const float* __restrict__ bwp,
            unsigned short* __restrict__ gbf)
{
    const int mc = blockIdx.x * 512;
    const int n0 = blockIdx.y * 8;
    const int tid = threadIdx.x;

    __shared__ float sxn[8], syn[8], szn[8], ssn[8];
    if (tid < 8) {
        const float x = xyz4[(n0 + tid) * 3 + 0];
        const float y = xyz4[(n0 + tid) * 3 + 1];
        const float z = xyz4[(n0 + tid) * 3 + 2];
        sxn[tid] = x; syn[tid] = y; szn[tid] = z; ssn[tid] = x*x + y*y + z*z;
    }
    __syncthreads();

    const float bw = bwp[0];
    const float c2k = 1.0f / (2.0f * bw * bw);
    const int m0 = mc + tid * 2;

    const float x0 = xyz4[m0 * 3 + 0], y0 = xyz4[m0 * 3 + 1], z0 = xyz4[m0 * 3 + 2];
    const float x1 = xyz4[m0 * 3 + 3], y1 = xyz4[m0 * 3 + 4], z1 = xyz4[m0 * 3 + 5];
    const float s0 = x0*x0 + y0*y0 + z0*z0;
    const float s1 = x1*x1 + y1*y1 + z1*z1;
    const float yh0 = y_hat[m0], yh1 = y_hat[m0 + 1];

#pragma unroll
    for (int r = 0; r < 8; r++) {
        const float xr = sxn[r], yr = syn[r], zr = szn[r], sr = ssn[r];
        const float d20 = sr + s0 - 2.0f * (xr*x0 + yr*y0 + zr*z0);
        const float d21 = sr + s1 - 2.0f * (xr*x1 + yr*y1 + zr*z1);
        const float g0 = __expf(-d20 * c2k) * yh0 + 1e-9f;
        const float g1 = __expf(-d21 * c2k) * yh1 + 1e-9f;
        const unsigned short mk2 = *reinterpret_cast<const unsigned short*>(
            mby + (long)(n0 + r) * 2048 + m0);
        ushort2 o;
        o.x = (mk2 & 0xff) ? f2bf(g0) : (unsigned short)0;
        o.y = (mk2 >> 8)   ? f2bf(g1) : (unsigned short)0;
        *reinterpret_cast<ushort2*>(gbf + (long)(n0 + r) * 2048 + m0) = o;
    }
}

// ---------------------------------------------------------------------------
// av_mfma: X = (E⊙g) @ v, E recomputed. grid (32 n-tiles of 64, 4 m-splits,
// 8 heads); wave = one 16-n subtile. vT AND kh staged per 128-m group into
// XOR-swizzled LDS. Score -> exp*g -> cvt_pk -> shfl exchange -> K=32 PV
// MFMA. (R7-verified.)
// ---------------------------------------------------------------------------
__global__ __launch_bounds__(256)
void av_mfma(const unsigned short* __restrict__ qh,
             const unsigned short* __restrict__ kh,
             const unsigned short* __restrict__ gbf,  // [2048][2048] masked
             const unsigned short* __restrict__ vT,   // [512][2048]
             const float* __restrict__ tptr,
             float* __restrict__ P)                   // [4][2048][512]
{
    const int h  = blockIdx.z;
    const int s  = blockIdx.y;
    const int bx = blockIdx.x;
    const int tid = threadIdx.x;
    const int wv = tid >> 6;
    const int lane = tid & 63;
    const int fr = lane & 15;
    const int g  = lane >> 4;
    const int koct = g * 8;
    const int n0 = bx * 64;

    __shared__ unsigned short vts[8192];      // [64 d][128 m] swizzled, 16 KB
    __shared__ unsigned short khs[8192];      // [128 m][64 dh] swizzled, 16 KB

    const float scale = 1.0f / (8.0f * tptr[0]);

    const unsigned short* Bp = qh + (long)(n0 + wv * 16 + fr) * 512 + h * 64;
    const bf16x8 b0 = *reinterpret_cast<const bf16x8*>(Bp + koct);
    const bf16x8 b1 = *reinterpret_cast<const bf16x8*>(Bp + 32 + koct);

    const unsigned short* grow = gbf + (long)(n0 + wv * 16 + fr) * 2048;
    const int sx = (fr & 7) << 4;

    f32x4 acc[4] = {};
    for (int grp = 0; grp < 4; grp++) {
        const int m0g = s * 512 + grp * 128;
        __syncthreads();
        // stage vT[h][0..63][m0g..+128) -> swizzled vts (rows 256 B)
#pragma unroll
        for (int i = 0; i < 4; i++) {
            const int bo = tid * 16 + i * 4096;
            const int row = bo >> 8;
            const int swz = bo ^ ((row & 7) << 4);
            const bf16x8 v = *reinterpret_cast<const bf16x8*>(
                vT + ((long)h * 64 + row) * 2048 + m0g + ((bo & 255) >> 1));
            *reinterpret_cast<bf16x8*>(reinterpret_cast<char*>(vts) + swz) = v;
        }
        // stage kh[m0g..+128)[h*64..+64) -> swizzled khs (rows 128 B)
#pragma unroll
        for (int i = 0; i < 4; i++) {
            const int bo = tid * 16 + i * 4096;
            const int row = bo >> 7;
            const int swz = bo ^ ((row & 7) << 4);
            const bf16x8 v = *reinterpret_cast<const bf16x8*>(
                kh + (long)(m0g + row) * 512 + h * 64 + ((bo & 127) >> 1));
            *reinterpret_cast<bf16x8*>(reinterpret_cast<char*>(khs) + swz) = v;
        }
        __syncthreads();
#pragma unroll
        for (int mblk = 0; mblk < 4; mblk++) {
            const int m0 = m0g + mblk * 32;
            // scores from LDS kh (swizzled, conflict-free)
            f32x4 c[2];
#pragma unroll
            for (int t = 0; t < 2; t++) {
                const int lr = mblk * 32 + t * 16 + fr;
                const int cbase = (lr << 7) + (g << 4);
                const bf16x8 alo = *reinterpret_cast<const bf16x8*>(
                    reinterpret_cast<const char*>(khs) + (cbase ^ sx));
                const bf16x8 ahi = *reinterpret_cast<const bf16x8*>(
                    reinterpret_cast<const char*>(khs) + ((cbase + 64) ^ sx));
                f32x4 cc = {};
                cc = __builtin_amdgcn_mfma_f32_16x16x32_bf16(alo, b0, cc, 0, 0, 0);
                cc = __builtin_amdgcn_mfma_f32_16x16x32_bf16(ahi, b1, cc, 0, 0, 0);
                c[t] = cc;
            }
            const ushort4 g0 = *reinterpret_cast<const ushort4*>(grow + m0 + 4 * g);
            const ushort4 g1 = *reinterpret_cast<const ushort4*>(grow + m0 + 16 + 4 * g);
            const unsigned int P0 = cvtpk(__expf(c[0][0]*scale)*bf2f(g0.x),
                                          __expf(c[0][1]*scale)*bf2f(g0.y));
            const unsigned int P1 = cvtpk(__expf(c[0][2]*scale)*bf2f(g0.z),
                                          __expf(c[0][3]*scale)*bf2f(g0.w));
            const unsigned int Q0 = cvtpk(__expf(c[1][0]*scale)*bf2f(g1.x),
                                          __expf(c[1][1]*scale)*bf2f(g1.y));
            const unsigned int Q1 = cvtpk(__expf(c[1][2]*scale)*bf2f(g1.z),
                                          __expf(c[1][3]*scale)*bf2f(g1.w));
            const bf16x8 fb = eg_exchange(P0, P1, Q0, Q1, g, fr);
#pragma unroll
            for (int dt = 0; dt < 4; dt++) {
                const int bofs = (((dt * 16 + fr) << 8) + mblk * 64 + g * 16) ^ sx;
                const bf16x8 avt = *reinterpret_cast<const bf16x8*>(
                    reinterpret_cast<const char*>(vts) + bofs);
                acc[dt] = __builtin_amdgcn_mfma_f32_16x16x32_bf16(avt, fb, acc[dt], 0, 0, 0);
            }
        }
    }

    float* Pp = P + (long)s * 1048576;
#pragma unroll
    for (int dt = 0; dt < 4; dt++)
        *reinterpret_cast<float4*>(
            &Pp[(long)(n0 + wv * 16 + fr) * 512 + h * 64 + dt * 16 + 4 * g]) =
            *reinterpret_cast<const float4*>(&acc[dt]);
}

// ---------------------------------------------------------------------------
// xc[n][d] bf16 = invz_h[n] * sum of 4 fp32 partials. 8 elems/thread.
// ---------------------------------------------------------------------------
__global__ __launch_bounds__(256)
void av_red(const float* __restrict__ P, const float* __restrict__ invzb,
            unsigned short* __restrict__ xc)
{
    const long idx = (long)(blockIdx.x * 256 + threadIdx.x) * 8;
    const int n = (int)(idx >> 9);
    const int d0 = (int)(idx & 511);
    const float iz = invzb[(d0 >> 6) * 2048 + n];
    float s[8] = {};
#pragma unroll
    for (int p = 0; p < 4; p++) {
        const float* pp = P + (long)p * 1048576 + idx;
        float4 a = *reinterpret_cast<const float4*>(pp);
        float4 b = *reinterpret_cast<const float4*>(pp + 4);
        s[0] += a.x; s[1] += a.y; s[2] += a.z; s[3] += a.w;
        s[4] += b.x; s[5] += b.y; s[6] += b.z; s[7] += b.w;
    }
    EU o;
#pragma unroll
    for (int j = 0; j < 8; j++) o.u[j] = f2bf(s[j] * iz);
    *reinterpret_cast<bf16x8*>(xc + idx) = o.v;
}

// ---------------------------------------------------------------------------
// out = xc @ Wo.T + bo via bf16 MFMA, fp32 out. grid (32 n-tiles, 8 d-tiles).
// ---------------------------------------------------------------------------
__global__ __launch_bounds__(256)
void out_mfma(const unsigned short* __restrict__ xc,
              const unsigned short* __restrict__ sW,   // seg 3 = Wo
              const float* __restrict__ bo,
              float* __restrict__ out)
{
    const int bx = blockIdx.x;
    const int by = blockIdx.y;
    const int wv = threadIdx.x >> 6;
    const int lane = threadIdx.x & 63;
    const int row  = lane & 15;
    const int koct = (lane >> 4) * 8;
    const int n0 = bx * 64;

    const unsigned short* Ap = xc + (long)(n0 + wv * 16 + row) * 512;
    const unsigned short* Bp = sW + 3L * 262144 + (long)(by * 64 + row) * 512;

    f32x4 acc[4] = {};
#pragma unroll
    for (int k0 = 0; k0 < 512; k0 += 32) {
        bf16x8 a = *reinterpret_cast<const bf16x8*>(Ap + k0 + koct);
#pragma unroll
        for (int t = 0; t < 4; t++) {
            bf16x8 b = *reinterpret_cast<const bf16x8*>(Bp + (long)(t * 16) * 512 + k0 + koct);
            acc[t] = __builtin_amdgcn_mfma_f32_16x16x32_bf16(a, b, acc[t], 0, 0, 0);
        }
    }

    const int rbase = n0 + wv * 16 + (lane >> 4) * 4;
    const int dcol = lane & 15;
#pragma unroll
    for (int t = 0; t < 4; t++) {
        const int col = by * 64 + t * 16 + dcol;
        const float bb = bo[col];
#pragma unroll
        for (int r = 0; r < 4; r++)
            out[(long)(rbase + r) * 512 + col] = acc[t][r] + bb;
    }
}

// ---------------------------------------------------------------------------
extern "C" void kernel_launch(void* const* d_in, const int* in_sizes, int n_in,
                              void* d_out, int out_size, void* d_ws, size_t ws_size,
                              hipStream_t stream)
{
    (void)in_sizes; (void)n_in; (void)out_size; (void)ws_size;

    const float* xyz   = (const float*)d_in[0];
    const float* strf  = (const float*)d_in[1];
    // d_in[2] esm_feat: dead code (DCE'd in reference)
    const float* yhat  = (const float*)d_in[3];
    const int*   dmask = (const int*)d_in[4];
    const float* tptr  = (const float*)d_in[5];
    const float* bwptr = (const float*)d_in[6];
    // d_in[7] max_iter = 5 (fixed)
    const float* Wq = (const float*)d_in[8];
    const float* bq = (const float*)d_in[9];
    const float* Wk = (const float*)d_in[10];
    const float* bk = (const float*)d_in[11];
    const float* Wv = (const float*)d_in[12];
    const float* bv = (const float*)d_in[13];
    const float* Wo = (const float*)d_in[14];
    const float* bo = (const float*)d_in[15];
    float* outp = (float*)d_out;

    char* wsb = (char*)d_ws;
    float* Ppart         = (float*)(wsb);                        // 16 MB
    unsigned short* xc   = (unsigned short*)(wsb + (16L << 20)); // 2 MB
    unsigned short* sA   = (unsigned short*)(wsb + (18L << 20)); // 2 MB
    unsigned short* sW   = (unsigned short*)(wsb + (20L << 20)); // 2 MB
    unsigned short* qh   = (unsigned short*)(wsb + (22L << 20)); // 2 MB
    unsigned short* kh   = (unsigned short*)(wsb + (24L << 20)); // 2 MB
    unsigned short* vT   = (unsigned short*)(wsb + (26L << 20)); // 2 MB
    float* xyzA          = (float*)(wsb + (28L << 20));
    float* xyzB          = xyzA + 8192;
    unsigned char* mby   = (unsigned char*)(wsb + (30L << 20));  // 4 MB
    float* Pzs           = (float*)(wsb + (34L << 20));          // [8][2048][8][2]f4, 4 MB
    unsigned short* gbf  = (unsigned short*)(wsb + (50L << 20)); // 8 MB
    float* invzb         = (float*)(wsb + (58L << 20));          // 64 KB

    dim3 blk(256, 1, 1);

    conv_all<<<dim3(3072), blk, 0, stream>>>(strf, Wq, Wk, Wv, Wo, dmask, sA, sW, mby);
    qkv_mfma<<<dim3(32, 8, 3), blk, 0, stream>>>(sA, sW, bq, bk, bv, qh, kh, vT);

    // 5 mean-shift iterations: LDS-staged fused sweep + tiny slice reduce
    const float* src = xyz;
    float* dsts[5] = {xyzA, xyzB, xyzA, xyzB, outp};
    for (int it = 0; it < 5; it++) {
        ms_swp<<<dim3(64, 8), blk, 0, stream>>>(qh, kh, mby, src, yhat, tptr, bwptr, Pzs);
        ms_fin<<<dim3(128), dim3(128), 0, stream>>>(Pzs, dsts[it], invzb, it == 4 ? 1 : 0);
        src = dsts[it];
    }

    g_kern<<<dim3(4, 256), blk, 0, stream>>>(xyzB, yhat, mby, bwptr, gbf);
    av_mfma<<<dim3(32, 4, 8), blk, 0, stream>>>(qh, kh, gbf, vT, tptr, Ppart);
    av_red<<<dim3(512), blk, 0, stream>>>(Ppart, invzb, xc);
    out_mfma<<<dim3(32, 8), blk, 0, stream>>>(xc, sW, bo, outp + 6144);
}